// Round 5
// baseline (10287.086 us; speedup 1.0000x reference)
//
#include <hip/hip_runtime.h>
#include <cstddef>
#include <cstdint>

#define T_STEPS 256
#define BATCH   512
#define NIN     128
#define NHID    1024
#define NWGS    256

typedef _Float16 half8  __attribute__((ext_vector_type(8)));
typedef _Float16 half4v __attribute__((ext_vector_type(4)));
typedef float    float4v __attribute__((ext_vector_type(4)));

__device__ __forceinline__ float sigmoid_f(float x) { return 1.0f / (1.0f + __expf(-x)); }
__device__ __forceinline__ float tanh_f(float x) {
    float ax = fabsf(x);
    float t  = __expf(-2.0f * ax);
    float r  = (1.0f - t) / (1.0f + t);
    return copysignf(r, x);
}

// LDS map (dynamic, ~154 KB)
#define WLDS_OFF  0         // 131072 B: weight B-frags [nt 4][kt 32][lane 64][16B]
#define WHF_OFF   131072    // 4096 B:  proj B-frags [kt 4][lane 64][16B] (kk0 roles)
#define ZS_OFF    135168    // 18432 B: per-wave z scratch (2304 B each, 16 rows x 36 f32)
#define ZW_BYTES  2304
#define HS_OFF    153600    // 4096 B:  per-wave h scratch (512 B each: 16 rows x 16 f16)
#define BIASG_OFF 157696    // 256 B:   gate bias [g 4][u 16] f32
#define BH_OFF    157952    // 32 B:    proj bias [u 8] f32
#define SMEM_BYTES 157984

// ---------------------------------------------------------------------------
// Tree grid barrier: 8 sub-counters (per bid&7 group of 32 WGs) fan into a
// master counter -> gen. Monotonic counters, never reset.
// Layout (uint32 idx): sub[g] at g*32, master at 256, gen at 320.
// ---------------------------------------------------------------------------
__device__ __forceinline__ void grid_barrier(uint32_t* bm, uint32_t target_gen,
                                             int grp) {
    __syncthreads();
    if (threadIdx.x == 0) {
        __threadfence();
        uint32_t old = __hip_atomic_fetch_add(bm + grp * 32, 1u, __ATOMIC_RELAXED,
                                              __HIP_MEMORY_SCOPE_AGENT);
        if (old == target_gen * 32u - 1u) {
            uint32_t mold = __hip_atomic_fetch_add(bm + 256, 1u, __ATOMIC_RELAXED,
                                                   __HIP_MEMORY_SCOPE_AGENT);
            if (mold == target_gen * 8u - 1u)
                __hip_atomic_store(bm + 320, target_gen, __ATOMIC_RELAXED,
                                   __HIP_MEMORY_SCOPE_AGENT);
        }
        uint32_t spins = 0;
        while (__hip_atomic_load(bm + 320, __ATOMIC_RELAXED,
                                 __HIP_MEMORY_SCOPE_AGENT) < target_gen) {
            __builtin_amdgcn_s_sleep(8);
            if (++spins > 20000000u) break;
        }
        __threadfence();
    }
    __syncthreads();
}

// ---------------------------------------------------------------------------
// One-time x -> fp16 A-frag conversion (unchanged layout).
// xf[t 256][mt 32][kt 4][512 halves]
// ---------------------------------------------------------------------------
__global__ __launch_bounds__(256)
void xconv_kernel(const float* __restrict__ x, _Float16* __restrict__ xf)
{
    __shared__ float xs[16][2][128];
    const int mt = blockIdx.x, tb = blockIdx.y;
    const int t = threadIdx.x;
    for (int tl = 0; tl < 8; ++tl) {
        __syncthreads();
#pragma unroll
        for (int i = 0; i < 4; ++i) {
            const int idx = t + i * 256;
            const int m = idx >> 6, rest = idx & 63;
            const int t2 = rest >> 5, k4 = rest & 31;
            float4v v = *(const float4v*)(x +
                ((size_t)(mt * 16 + m) * T_STEPS + (tb * 16 + tl * 2 + t2)) * NIN + k4 * 4);
            *(float4v*)&xs[m][t2][k4 * 4] = v;
        }
        __syncthreads();
#pragma unroll
        for (int i = 0; i < 2; ++i) {
            const int idx = t + i * 256;
            const int t2 = idx >> 8, rest = idx & 255;
            const int kt = rest >> 6, lane = rest & 63;
            half8 hv;
#pragma unroll
            for (int j = 0; j < 8; ++j)
                hv[j] = (_Float16)xs[lane & 15][t2][kt * 32 + (lane >> 4) * 8 + j];
            const int tg = tb * 16 + tl * 2 + t2;
            *(half8*)(xf + (((size_t)tg * 32 + mt) * 4 + kt) * 512 + lane * 8) = hv;
        }
    }
}

// ---------------------------------------------------------------------------
// Persistent kernel, K-SPLIT roles. 256 WGs x 512 thr, 1 WG/CU.
// role = bid&3: 0=L0kk0, 1=L0kk1, 2=L1kk0, 3=L1kk1; slice = bid>>2 (16 units).
// Each WG: GEMM M=512, N=64 (4 gate-nt), K=1024 (32 kt); weights 128 KB LDS.
// A-read 1 MB/WG/phase (half of old) -> per-XCD L2 traffic ~34 MB vs 64 MB.
// kk0 produces f16 partials (non-recurrent K-half) one phase early;
// kk1 adds partial + recurrent K-half + epilogue. Schedule (timestep t):
//   proj(t)@p=t -> partial1(t)@t+1 -> h1(t)@t+2 -> partial2(t)@t+3 -> h2(t)@t+4
// All producer->consumer edges cross exactly one grid barrier.
// ---------------------------------------------------------------------------
__global__ __launch_bounds__(512, 2)
void persist_kernel(const float* __restrict__ k1, const float* __restrict__ b1,
                    const float* __restrict__ k2, const float* __restrict__ b2,
                    const float* __restrict__ W_h, const float* __restrict__ b_h,
                    const _Float16* __restrict__ xf,
                    uint8_t* wsb, float* __restrict__ out,
                    uint32_t* barrier_mem)
{
    extern __shared__ __align__(16) char smem[];
    const size_t MB = 1024 * 1024;
    _Float16* PFb[2]  = {(_Float16*)(wsb + 0 * MB), (_Float16*)(wsb + 1 * MB)};
    _Float16* H1f[2]  = {(_Float16*)(wsb + 2 * MB), (_Float16*)(wsb + 3 * MB)};
    _Float16* H2f[2]  = {(_Float16*)(wsb + 4 * MB), (_Float16*)(wsb + 5 * MB)};
    uint8_t*  partbase = wsb + 6 * MB;   // [par 2][layer 2] x 4MB, slice*64KB inside

    const int tid = threadIdx.x;
    const int w = tid >> 6, lane = tid & 63;
    const int q = lane >> 4, n16 = lane & 15;
    const int bid = blockIdx.x;
    const int role = bid & 3;
    const int slice = bid >> 2;           // 0..63
    const int layer = role >> 1;
    const int kk = role & 1;
    const int u0h = slice * 16;           // 16 units per slice
    const int pu0 = (layer * 64 + slice) * 8;   // proj units (kk0 roles)

    const float* ksrc = layer ? k2 : k1;
    const float* bsrc = layer ? b2 : b1;

    // ---- init: weight slice f32 -> fp16 frags in LDS ----
    // [nt 4][kt 32]: nt = gate; col = nt*1024 + u0h + n16; k = kk*1024 + kt*32 + q*8 + j
    {
#pragma unroll 1
        for (int i = 0; i < 16; ++i) {
            const int ti = w * 16 + i;
            const int nt = ti >> 5, kt = ti & 31;
            const int col = nt * 1024 + u0h + n16;
            half8 hv;
#pragma unroll
            for (int j = 0; j < 8; ++j)
                hv[j] = (_Float16)ksrc[(size_t)(kk * 1024 + kt * 32 + q * 8 + j) * 4096 + col];
            *(half8*)(smem + WLDS_OFF + (nt * 32 + kt) * 1024 + lane * 16) = hv;
        }
    }
    if (tid < 64)
        ((float*)(smem + BIASG_OFF))[tid] = bsrc[(tid >> 4) * 1024 + u0h + (tid & 15)];
    if (kk == 0) {   // proj on kk0 roles (128 WGs x 8 units)
        if (tid < 256) {
            const int kt = tid >> 6, ln = tid & 63;
            const int nn = ln & 15;
            half8 hv;
#pragma unroll
            for (int j = 0; j < 8; ++j) {
                float v = (nn < 8)
                    ? W_h[(size_t)(kt * 32 + (ln >> 4) * 8 + j) * NHID + pu0 + nn] : 0.f;
                hv[j] = (_Float16)v;
            }
            *(half8*)(smem + WHF_OFF + kt * 1024 + ln * 16) = hv;
        }
        if (tid < 8) ((float*)(smem + BH_OFF))[tid] = b_h[pu0 + tid];
    }
    __syncthreads();

    const float* bg = (const float*)(smem + BIASG_OFF);
    const float* bh = (const float*)(smem + BH_OFF);
    float* zw = (float*)(smem + ZS_OFF + w * ZW_BYTES);     // [16 rows][36 f32]
    _Float16* hw = (_Float16*)(smem + HS_OFF + w * 512);    // [16 rows][16 u]

    // c state: lane owns row n16, units {q*2, q*2+1, q*2+8, q*2+9} per mt
    float cst[4][4];
#pragma unroll
    for (int mt = 0; mt < 4; ++mt)
#pragma unroll
        for (int uu = 0; uu < 4; ++uu) cst[mt][uu] = 0.f;

    // ---- proj body (kk0 roles): pf(t) slice [512 x 8 units] -> PF frags ----
    auto proj_step = [&](int tstep, _Float16* PFdst) {
        float4v pacc[4];
#pragma unroll
        for (int mt = 0; mt < 4; ++mt) pacc[mt] = (float4v){0.f, 0.f, 0.f, 0.f};
        half8 Bp[4];
        half8 Ap[4][4];
#pragma unroll
        for (int kt = 0; kt < 4; ++kt) {
            Bp[kt] = *(const half8*)(smem + WHF_OFF + kt * 1024 + lane * 16);
#pragma unroll
            for (int mt = 0; mt < 4; ++mt)
                Ap[kt][mt] = *(const half8*)(xf +
                    (((size_t)tstep * 32 + (w * 4 + mt)) * 4 + kt) * 512 + lane * 8);
        }
#pragma unroll
        for (int kt = 0; kt < 4; ++kt)
#pragma unroll
            for (int mt = 0; mt < 4; ++mt)
                pacc[mt] = __builtin_amdgcn_mfma_f32_16x16x32_f16(Ap[kt][mt], Bp[kt], pacc[mt], 0, 0, 0);
        const int sp = layer * 64 + slice;      // 0..127, 8-unit group id
#pragma unroll 1
        for (int mt = 0; mt < 4; ++mt) {
            if (n16 < 8) {
#pragma unroll
                for (int r = 0; r < 4; ++r)
                    zw[(q * 4 + r) * 9 + n16] = pacc[mt][r];   // stride 9: conflict-free
            }
            if (lane < 16) {
                half8 hv;
#pragma unroll
                for (int u = 0; u < 8; ++u)
                    hv[u] = (_Float16)fmaxf(zw[lane * 9 + u] + bh[u], 0.f);
                const int mtg = w * 4 + mt;
                *(half8*)(PFdst + ((size_t)mtg * 32 + (sp >> 2)) * 512
                                + ((sp & 3) * 16 + lane) * 8) = hv;
            }
        }
    };

    // ---- GEMM core: M512 x N64 x K1024, depth-3 counted-vmcnt asm pipeline.
    // kk0: store acc as f16 partial. kk1: acc pre-init from partial, epilogue.
    auto gemm_core = [&](const _Float16* Asrc, _Float16* part_out,
                         const _Float16* part_in, _Float16* hdst, float* outp) {
        float4v acc[4][4];
        if (part_in) {
#pragma unroll
            for (int mt = 0; mt < 4; ++mt)
#pragma unroll
                for (int nt = 0; nt < 4; ++nt) {
                    half4v v = *(const half4v*)(part_in +
                        (((size_t)(w * 16 + mt * 4 + nt)) * 64 + lane) * 4);
                    acc[mt][nt] = (float4v){(float)v[0], (float)v[1],
                                            (float)v[2], (float)v[3]};
                }
            __builtin_amdgcn_sched_barrier(0);   // drain partial loads before asm pipe
        } else {
#pragma unroll
            for (int mt = 0; mt < 4; ++mt)
#pragma unroll
                for (int nt = 0; nt < 4; ++nt)
                    acc[mt][nt] = (float4v){0.f, 0.f, 0.f, 0.f};
        }
        const char* aw[4];
#pragma unroll
        for (int mt = 0; mt < 4; ++mt)
            aw[mt] = (const char*)Asrc + (size_t)(w * 4 + mt) * 32768 + lane * 16;

        half8 G0[8], G1[8], G2[8];   // 3 groups x 2 kt x 4 mt

#define ISSUE2(buf, kb)                                                         \
        do {                                                                    \
            _Pragma("unroll")                                                   \
            for (int kq = 0; kq < 2; ++kq) {                                    \
                _Pragma("unroll")                                               \
                for (int mt = 0; mt < 4; ++mt)                                  \
                    asm volatile("global_load_dwordx4 %0, %1, off"              \
                                 : "=&v"(buf[kq * 4 + mt])                      \
                                 : "v"(aw[mt] + (size_t)((kb) + kq) * 1024));   \
            }                                                                   \
        } while (0)

#define WAITG(n, buf)                                                           \
        do {                                                                    \
            asm volatile("s_waitcnt vmcnt(" #n ")"                              \
                : "+v"(buf[0]), "+v"(buf[1]), "+v"(buf[2]), "+v"(buf[3]),       \
                  "+v"(buf[4]), "+v"(buf[5]), "+v"(buf[6]), "+v"(buf[7]));      \
            __builtin_amdgcn_sched_barrier(0);                                  \
        } while (0)

#define MFMA2(buf, kb)                                                          \
        do {                                                                    \
            _Pragma("unroll")                                                   \
            for (int kq = 0; kq < 2; ++kq) {                                    \
                half8 Bv[4];                                                    \
                _Pragma("unroll")                                               \
                for (int nt = 0; nt < 4; ++nt)                                  \
                    Bv[nt] = *(const half8*)(smem + WLDS_OFF + (nt * 32         \
                              + (kb) + kq) * 1024 + lane * 16);                 \
                _Pragma("unroll")                                               \
                for (int mt = 0; mt < 4; ++mt) {                                \
                    _Pragma("unroll")                                           \
                    for (int nt = 0; nt < 4; ++nt)                              \
                        acc[mt][nt] = __builtin_amdgcn_mfma_f32_16x16x32_f16(   \
                            buf[kq * 4 + mt], Bv[nt], acc[mt][nt], 0, 0, 0);    \
                }                                                               \
            }                                                                   \
        } while (0)

        ISSUE2(G0, 0);
        ISSUE2(G1, 2);
        ISSUE2(G2, 4);               // 24 outstanding
#pragma unroll 1
        for (int g3 = 0; g3 < 4; ++g3) {
            const int kb = g3 * 6;
            WAITG(16, G0);  MFMA2(G0, kb);      ISSUE2(G0, kb + 6);
            WAITG(16, G1);  MFMA2(G1, kb + 2);  ISSUE2(G1, kb + 8);
            WAITG(16, G2);  MFMA2(G2, kb + 4);  ISSUE2(G2, kb + 10);
        }
        // after loop: G0=kt24, G1=kt26, G2=kt28; kts 30-31 unissued
        WAITG(16, G0);  MFMA2(G0, 24);  ISSUE2(G0, 30);
        WAITG(16, G1);  MFMA2(G1, 26);
        WAITG(8,  G2);  MFMA2(G2, 28);
        WAITG(0,  G0);  MFMA2(G0, 30);
#undef ISSUE2
#undef WAITG
#undef MFMA2

        if (part_out) {
            // store f16 partial in C-frag-linear layout (fully coalesced)
#pragma unroll
            for (int mt = 0; mt < 4; ++mt)
#pragma unroll
                for (int nt = 0; nt < 4; ++nt) {
                    half4v v = {(_Float16)acc[mt][nt][0], (_Float16)acc[mt][nt][1],
                                (_Float16)acc[mt][nt][2], (_Float16)acc[mt][nt][3]};
                    *(half4v*)(part_out +
                        (((size_t)(w * 16 + mt * 4 + nt)) * 64 + lane) * 4) = v;
                }
            return;
        }

        // ---- epilogue (kk1): two zw half-passes per mt, 16 units ----
#pragma unroll 1
        for (int mt = 0; mt < 4; ++mt) {
            float zi[4], zj[4], zf[4], zo[4];
            // pass 1: gates i (nt0), j (nt1)
#pragma unroll
            for (int r = 0; r < 4; ++r) {
                zw[(q * 4 + r) * 36 + n16]      = acc[mt][0][r];
                zw[(q * 4 + r) * 36 + 16 + n16] = acc[mt][1][r];
            }
#pragma unroll
            for (int uu = 0; uu < 4; ++uu) {
                const int u = q * 2 + (uu & 1) + (uu >> 1) * 8;
                zi[uu] = zw[n16 * 36 + u]      + bg[u];
                zj[uu] = zw[n16 * 36 + 16 + u] + bg[16 + u];
            }
            // pass 2: gates f (nt2), o (nt3)
#pragma unroll
            for (int r = 0; r < 4; ++r) {
                zw[(q * 4 + r) * 36 + n16]      = acc[mt][2][r];
                zw[(q * 4 + r) * 36 + 16 + n16] = acc[mt][3][r];
            }
#pragma unroll
            for (int uu = 0; uu < 4; ++uu) {
                const int u = q * 2 + (uu & 1) + (uu >> 1) * 8;
                zf[uu] = zw[n16 * 36 + u]      + bg[32 + u];
                zo[uu] = zw[n16 * 36 + 16 + u] + bg[48 + u];
            }
#pragma unroll
            for (int uu = 0; uu < 4; ++uu) {
                const int u = q * 2 + (uu & 1) + (uu >> 1) * 8;
                float c = cst[mt][uu] * sigmoid_f(zf[uu] + 1.0f)
                        + sigmoid_f(zi[uu]) * tanh_f(zj[uu]);
                cst[mt][uu] = c;
                float h = tanh_f(c) * sigmoid_f(zo[uu]);
                hw[n16 * 16 + u] = (_Float16)h;
                if (outp) {
                    const int row = (w * 4 + mt) * 16 + n16;
                    outp[(size_t)row * NHID + u0h + u] = h;
                }
            }
            // h-frag write: 16 rows x 2 kgrps via lanes 0..31
            if (lane < 32) {
                const int row = lane & 15, kg = lane >> 4;
                half8 hv = *(half8*)(hw + row * 16 + kg * 8);
                const int mtg = w * 4 + mt;
                *(half8*)(hdst + ((size_t)mtg * 32 + (slice >> 1)) * 512
                          + (((slice & 1) * 2 + kg) * 16 + row) * 8) = hv;
            }
        }
    };

    auto part_ptr = [&](int par, int lay) -> _Float16* {
        return (_Float16*)(partbase + ((size_t)(par * 2 + lay)) * 4 * MB
                           + (size_t)slice * 65536);
    };

    // ---- phases ----
    for (int p = 0; p <= 259; ++p) {
        if (role == 0) {                       // L0 kk0: partial1(t=p-1) + proj(p)
            if (p >= 1 && p <= 256)
                gemm_core(PFb[(p - 1) & 1], part_ptr((p - 1) & 1, 0),
                          nullptr, nullptr, nullptr);
            if (p <= 255) proj_step(p, PFb[p & 1]);
        } else if (role == 1) {                // L0 kk1: h1(t=p-2)
            if (p >= 2 && p <= 257) {
                const int t = p - 2;
                gemm_core(H1f[(t - 1) & 1], nullptr,
                          part_ptr(t & 1, 0), H1f[t & 1], nullptr);
            }
        } else if (role == 2) {                // L1 kk0: partial2(t=p-3) + proj(p)
            if (p >= 3 && p <= 258)
                gemm_core(H1f[(p - 3) & 1], part_ptr((p - 3) & 1, 1),
                          nullptr, nullptr, nullptr);
            if (p <= 255) proj_step(p, PFb[p & 1]);
        } else {                               // L1 kk1: h2(t=p-4)
            if (p >= 4 && p <= 259) {
                const int t = p - 4;
                gemm_core(H2f[(t - 1) & 1], nullptr,
                          part_ptr(t & 1, 1), H2f[t & 1],
                          (t == 255) ? out : nullptr);
            }
        }
        grid_barrier(barrier_mem, (uint32_t)(p + 1), bid & 7);
    }
}

// ---------------------------------------------------------------------------
extern "C" void kernel_launch(void* const* d_in, const int* in_sizes, int n_in,
                              void* d_out, int out_size, void* d_ws, size_t ws_size,
                              hipStream_t stream)
{
    const float* x   = (const float*)d_in[0];
    const float* W_h = (const float*)d_in[1];
    const float* b_h = (const float*)d_in[2];
    const float* k1  = (const float*)d_in[3];
    const float* b1  = (const float*)d_in[4];
    const float* k2  = (const float*)d_in[5];
    const float* b2  = (const float*)d_in[6];
    float* out = (float*)d_out;

    const size_t MB = 1024 * 1024;
    uint8_t* wsb = (uint8_t*)d_ws;
    // 0-6 MB: PF[2],H1f[2],H2f[2] frag buffers (zeroed)
    // 6-22 MB: f16 partials [par 2][layer 2] x 4 MB
    // 22-54 MB: xf ; barrier @ 54 MB
    _Float16* xf = (_Float16*)(wsb + 22 * MB);
    uint32_t* barrier_mem = (uint32_t*)(wsb + 54 * MB);

    hipFuncSetAttribute((const void*)persist_kernel,
                        hipFuncAttributeMaxDynamicSharedMemorySize, SMEM_BYTES);

    hipMemsetAsync(wsb, 0, 6 * MB, stream);          // zero frag buffers
    hipMemsetAsync(barrier_mem, 0, 4096, stream);
    xconv_kernel<<<dim3(32, 16), 256, 0, stream>>>(x, xf);
    persist_kernel<<<NWGS, 512, SMEM_BYTES, stream>>>(
        k1, b1, k2, b2, W_h, b_h, xf, wsb, out, barrier_mem);
}

// Round 6
// 9751.392 us; speedup vs baseline: 1.0549x; 1.0549x over previous
//
#include <hip/hip_runtime.h>
#include <cstddef>
#include <cstdint>

#define T_STEPS 256
#define BATCH   512
#define NIN     128
#define NHID    1024
#define NWGS    256

typedef _Float16 half8  __attribute__((ext_vector_type(8)));
typedef float    float4v __attribute__((ext_vector_type(4)));
typedef float    float2v __attribute__((ext_vector_type(2)));

__device__ __forceinline__ float sigmoid_f(float x) { return 1.0f / (1.0f + __expf(-x)); }
__device__ __forceinline__ float tanh_f(float x) {
    float ax = fabsf(x);
    float t  = __expf(-2.0f * ax);
    float r  = (1.0f - t) / (1.0f + t);
    return copysignf(r, x);
}

// LDS map (identical to R4's proven map)
#define WLDS_OFF  0         // 131072 B: weight B-frags [nt 2][kt 64][lane 64][16B]
                            //   kt 0..31 = W rows 0..1023 (static), 32..63 = rows 1024..2047 (rec)
#define WHF_OFF   131072    // 4096 B:  proj B-frags [kt 4][lane 64][16B] (proj WGs)
#define ZS_OFF    135168    // 18432 B: per-wave z scratch (2304 B each, 16 rows x 36 f32)
#define ZW_BYTES  2304
#define HS_OFF    153600    // 2048 B:  per-wave h scratch (256 B each)
#define BIASG_OFF 155648    // 128 B:   gate bias [g 4][u 8] f32
#define BH_OFF    155776    // 32 B:    proj bias [u 8] f32
#define SMEM_BYTES 155808

// ---------------------------------------------------------------------------
// Tree grid barrier (proven R4): 8 sub-counters fan into master -> gen.
// Layout (uint32 idx): sub[g] at g*32, master at 256, gen at 320.
// ---------------------------------------------------------------------------
__device__ __forceinline__ void grid_barrier(uint32_t* bm, uint32_t target_gen,
                                             int grp) {
    __syncthreads();
    if (threadIdx.x == 0) {
        __threadfence();
        uint32_t old = __hip_atomic_fetch_add(bm + grp * 32, 1u, __ATOMIC_RELAXED,
                                              __HIP_MEMORY_SCOPE_AGENT);
        if (old == target_gen * 32u - 1u) {
            uint32_t mold = __hip_atomic_fetch_add(bm + 256, 1u, __ATOMIC_RELAXED,
                                                   __HIP_MEMORY_SCOPE_AGENT);
            if (mold == target_gen * 8u - 1u)
                __hip_atomic_store(bm + 320, target_gen, __ATOMIC_RELAXED,
                                   __HIP_MEMORY_SCOPE_AGENT);
        }
        uint32_t spins = 0;
        while (__hip_atomic_load(bm + 320, __ATOMIC_RELAXED,
                                 __HIP_MEMORY_SCOPE_AGENT) < target_gen) {
            __builtin_amdgcn_s_sleep(8);
            if (++spins > 20000000u) break;
        }
        __threadfence();
    }
    __syncthreads();
}

// ---------------------------------------------------------------------------
// One-time x -> fp16 A-frag conversion (unchanged).
// xf[t 256][mt 32][kt 4][512 halves]
// ---------------------------------------------------------------------------
__global__ __launch_bounds__(256)
void xconv_kernel(const float* __restrict__ x, _Float16* __restrict__ xf)
{
    __shared__ float xs[16][2][128];
    const int mt = blockIdx.x, tb = blockIdx.y;
    const int t = threadIdx.x;
    for (int tl = 0; tl < 8; ++tl) {
        __syncthreads();
#pragma unroll
        for (int i = 0; i < 4; ++i) {
            const int idx = t + i * 256;
            const int m = idx >> 6, rest = idx & 63;
            const int t2 = rest >> 5, k4 = rest & 31;
            float4v v = *(const float4v*)(x +
                ((size_t)(mt * 16 + m) * T_STEPS + (tb * 16 + tl * 2 + t2)) * NIN + k4 * 4);
            *(float4v*)&xs[m][t2][k4 * 4] = v;
        }
        __syncthreads();
#pragma unroll
        for (int i = 0; i < 2; ++i) {
            const int idx = t + i * 256;
            const int t2 = idx >> 8, rest = idx & 255;
            const int kt = rest >> 6, lane = rest & 63;
            half8 hv;
#pragma unroll
            for (int j = 0; j < 8; ++j)
                hv[j] = (_Float16)xs[lane & 15][t2][kt * 32 + (lane >> 4) * 8 + j];
            const int tg = tb * 16 + tl * 2 + t2;
            *(half8*)(xf + (((size_t)tg * 32 + mt) * 4 + kt) * 512 + lane * 8) = hv;
        }
    }
}

// ---------------------------------------------------------------------------
// Persistent kernel, UNIFIED CARRY-ACC2. 256 WGs x 512 thr, 1 WG/CU.
// xcd = bid&7; layer = xcd>>2; s = (xcd&3)*32 + (bid>>3); u0 = s*8.
// Per phase p each WG: (a) finish z(t) = carried acc2 (static K-half, done
// last phase) + rec K-half streamed now + epilogue -> h(t) single write;
// (b) compute next phase's static K-half into acc2 (pf for L0, h1 for L1).
// Schedule: L0 finishes h1(t=p) at p; L1 finishes h2(t=p-2) at p.
// proj (pf(p+2)) on odd-s WGs of BOTH layers (balanced).
// A-buffers: PF/H1/H2 rings of 2, each [mt 32][kt 32][512] f16 = 1 MB.
// ---------------------------------------------------------------------------
__global__ __launch_bounds__(512, 2)
void persist_kernel(const float* __restrict__ k1, const float* __restrict__ b1,
                    const float* __restrict__ k2, const float* __restrict__ b2,
                    const float* __restrict__ W_h, const float* __restrict__ b_h,
                    const _Float16* __restrict__ xf,
                    uint8_t* wsb, float* __restrict__ out,
                    uint32_t* barrier_mem)
{
    extern __shared__ __align__(16) char smem[];
    const size_t MB = 1024 * 1024;
    _Float16* PF[2] = {(_Float16*)(wsb + 0 * MB), (_Float16*)(wsb + 1 * MB)};
    _Float16* H1[2] = {(_Float16*)(wsb + 2 * MB), (_Float16*)(wsb + 3 * MB)};
    _Float16* H2[2] = {(_Float16*)(wsb + 4 * MB), (_Float16*)(wsb + 5 * MB)};

    const int tid = threadIdx.x;
    const int w = tid >> 6, lane = tid & 63;
    const int q = lane >> 4, n16 = lane & 15;
    const int bid = blockIdx.x;
    const int xcd = bid & 7;
    const int layer = xcd >> 2;
    const int s = (xcd & 3) * 32 + (bid >> 3);   // 0..127 per layer
    const int u0 = s * 8;
    const bool doProj = (s & 1) != 0;            // 64 per layer -> 128 slices
    const int sp = layer * 64 + (s >> 1);        // proj slice 0..127
    const int pu0 = sp * 8;

    const float* ksrc = layer ? k2 : k1;
    const float* bsrc = layer ? b2 : b1;

    // ---- init: weight slice f32 -> fp16 frags in LDS (R4 verbatim) ----
    {
#pragma unroll 1
        for (int i = 0; i < 16; ++i) {
            const int kt = w * 8 + (i & 7);
            const int nt = i >> 3;
            const int colg = (nt * 2 + (n16 >> 3)) * 1024 + u0 + (n16 & 7);
            half8 hv;
#pragma unroll
            for (int j = 0; j < 8; ++j)
                hv[j] = (_Float16)ksrc[(size_t)(kt * 32 + q * 8 + j) * 4096 + colg];
            *(half8*)(smem + WLDS_OFF + (nt * 64 + kt) * 1024 + lane * 16) = hv;
        }
    }
    if (tid < 32)
        ((float*)(smem + BIASG_OFF))[tid] = bsrc[(tid >> 3) * 1024 + u0 + (tid & 7)];
    if (doProj) {
        if (tid < 256) {
            const int kt = tid >> 6, ln = tid & 63;
            const int nn = ln & 15;
            half8 hv;
#pragma unroll
            for (int j = 0; j < 8; ++j) {
                float v = (nn < 8)
                    ? W_h[(size_t)(kt * 32 + (ln >> 4) * 8 + j) * NHID + pu0 + nn] : 0.f;
                hv[j] = (_Float16)v;
            }
            *(half8*)(smem + WHF_OFF + kt * 1024 + ln * 16) = hv;
        }
        if (tid < 8) ((float*)(smem + BH_OFF))[tid] = b_h[pu0 + tid];
    }
    __syncthreads();

    const float* bg = (const float*)(smem + BIASG_OFF);
    const float* bh = (const float*)(smem + BH_OFF);
    float* zw = (float*)(smem + ZS_OFF + w * ZW_BYTES);     // [16 rows][36 f32]
    _Float16* hw = (_Float16*)(smem + HS_OFF + w * 256);    // [16 rows][8 u]

    // persistent state
    float cst[4][2];
#pragma unroll
    for (int mt = 0; mt < 4; ++mt) { cst[mt][0] = 0.f; cst[mt][1] = 0.f; }
    float4v accA[4][2];                 // z accumulator, carried across barrier
#pragma unroll
    for (int mt = 0; mt < 4; ++mt) {
        accA[mt][0] = (float4v){0.f, 0.f, 0.f, 0.f};
        accA[mt][1] = (float4v){0.f, 0.f, 0.f, 0.f};
    }
    half8 G0[8], G1[8], G2[8];          // 3 load groups x 2 kt x 4 mt
    const char* aw[4];

    auto set_aw = [&](const _Float16* A) {
#pragma unroll
        for (int mt = 0; mt < 4; ++mt)
            aw[mt] = (const char*)A + (size_t)(w * 4 + mt) * 32768 + lane * 16;
    };
    auto zero_acc = [&]() {
#pragma unroll
        for (int mt = 0; mt < 4; ++mt) {
            accA[mt][0] = (float4v){0.f, 0.f, 0.f, 0.f};
            accA[mt][1] = (float4v){0.f, 0.f, 0.f, 0.f};
        }
    };

#define ISSUE2(buf, kb)                                                         \
        do {                                                                    \
            _Pragma("unroll")                                                   \
            for (int kq = 0; kq < 2; ++kq) {                                    \
                _Pragma("unroll")                                               \
                for (int mt = 0; mt < 4; ++mt)                                  \
                    asm volatile("global_load_dwordx4 %0, %1, off"              \
                                 : "=&v"(buf[kq * 4 + mt])                      \
                                 : "v"(aw[mt] + (size_t)((kb) + kq) * 1024));   \
            }                                                                   \
        } while (0)

#define WAITG(n, buf)                                                           \
        do {                                                                    \
            asm volatile("s_waitcnt vmcnt(" #n ")"                              \
                : "+v"(buf[0]), "+v"(buf[1]), "+v"(buf[2]), "+v"(buf[3]),       \
                  "+v"(buf[4]), "+v"(buf[5]), "+v"(buf[6]), "+v"(buf[7]));      \
            __builtin_amdgcn_sched_barrier(0);                                  \
        } while (0)

#define MFMA2G(buf, kb, lb)                                                     \
        do {                                                                    \
            _Pragma("unroll")                                                   \
            for (int kq = 0; kq < 2; ++kq) {                                    \
                half8 B0 = *(const half8*)(smem + WLDS_OFF + (lb)               \
                              + (size_t)((kb) + kq) * 1024 + lane * 16);        \
                half8 B1 = *(const half8*)(smem + WLDS_OFF + 65536 + (lb)       \
                              + (size_t)((kb) + kq) * 1024 + lane * 16);        \
                _Pragma("unroll")                                               \
                for (int mt = 0; mt < 4; ++mt)                                  \
                    accA[mt][0] = __builtin_amdgcn_mfma_f32_16x16x32_f16(       \
                        buf[kq * 4 + mt], B0, accA[mt][0], 0, 0, 0);            \
                _Pragma("unroll")                                               \
                for (int mt = 0; mt < 4; ++mt)                                  \
                    accA[mt][1] = __builtin_amdgcn_mfma_f32_16x16x32_f16(       \
                        buf[kq * 4 + mt], B1, accA[mt][1], 0, 0, 0);            \
            }                                                                   \
        } while (0)

    // issue the first 3 groups (kt 0..5) of buffer A
    auto pipe_issue = [&](const _Float16* A) {
        set_aw(A);
        ISSUE2(G0, 0); ISSUE2(G1, 2); ISSUE2(G2, 4);
    };
    // run the remaining schedule over 32 kt (groups 0..30), counted vmcnt
    auto pipe_run = [&](const _Float16* A, int lb) {
        set_aw(A);
#pragma unroll 1
        for (int g3 = 0; g3 < 4; ++g3) {
            const int kb = g3 * 6;
            WAITG(16, G0);  MFMA2G(G0, kb, lb);      ISSUE2(G0, kb + 6);
            WAITG(16, G1);  MFMA2G(G1, kb + 2, lb);  ISSUE2(G1, kb + 8);
            WAITG(16, G2);  MFMA2G(G2, kb + 4, lb);  ISSUE2(G2, kb + 10);
        }
        // handled 0..22; outstanding {24(G0),26(G1),28(G2)}
        WAITG(16, G0);  MFMA2G(G0, 24, lb);  ISSUE2(G0, 30);
        WAITG(16, G1);  MFMA2G(G1, 26, lb);
        WAITG(8,  G2);  MFMA2G(G2, 28, lb);
        WAITG(0,  G0);  MFMA2G(G0, 30, lb);
    };

    // ---- epilogue: accA -> gates -> c,h ; single h-frag write ----
    auto epilogue = [&](_Float16* hdst, float* outp) {
#pragma unroll 1
        for (int mt = 0; mt < 4; ++mt) {
#pragma unroll
            for (int nt = 0; nt < 2; ++nt)
#pragma unroll
                for (int r = 0; r < 4; ++r)
                    zw[(q * 4 + r) * 36 + nt * 16 + n16] = accA[mt][nt][r];
            const float* zr = zw + n16 * 36 + q * 2;
            float2v vi = *(const float2v*)(zr + 0);
            float2v vj = *(const float2v*)(zr + 8);
            float2v vf = *(const float2v*)(zr + 16);
            float2v vo = *(const float2v*)(zr + 24);
            float hvals[2];
#pragma unroll
            for (int uu = 0; uu < 2; ++uu) {
                const int u = q * 2 + uu;
                const float zi = vi[uu] + bg[u];
                const float zj = vj[uu] + bg[8 + u];
                const float zf = vf[uu] + bg[16 + u];
                const float zo = vo[uu] + bg[24 + u];
                float c = cst[mt][uu] * sigmoid_f(zf + 1.0f) + sigmoid_f(zi) * tanh_f(zj);
                cst[mt][uu] = c;
                hvals[uu] = tanh_f(c) * sigmoid_f(zo);
            }
            hw[n16 * 8 + q * 2 + 0] = (_Float16)hvals[0];
            hw[n16 * 8 + q * 2 + 1] = (_Float16)hvals[1];
            if (outp) {
                const int row = (w * 4 + mt) * 16 + n16;
                outp[(size_t)row * NHID + u0 + q * 2 + 0] = hvals[0];
                outp[(size_t)row * NHID + u0 + q * 2 + 1] = hvals[1];
            }
            if (lane < 16) {
                half8 hv = *(half8*)(hw + lane * 8);
                const int mtg = w * 4 + mt;
                *(half8*)(hdst + ((size_t)mtg * 32 + (s >> 2)) * 512
                          + ((s & 3) * 16 + lane) * 8) = hv;
            }
        }
    };

    // ---- proj (odd-s WGs): pf(tstep) -> PF frag buffer ----
    auto proj_step = [&](int tstep, _Float16* PFdst) {
        float4v pacc[4];
#pragma unroll
        for (int mt = 0; mt < 4; ++mt) pacc[mt] = (float4v){0.f, 0.f, 0.f, 0.f};
        half8 Bp[4];
        half8 Ap[4][4];
#pragma unroll
        for (int kt = 0; kt < 4; ++kt) {
            Bp[kt] = *(const half8*)(smem + WHF_OFF + kt * 1024 + lane * 16);
#pragma unroll
            for (int mt = 0; mt < 4; ++mt)
                Ap[kt][mt] = *(const half8*)(xf +
                    (((size_t)tstep * 32 + (w * 4 + mt)) * 4 + kt) * 512 + lane * 8);
        }
#pragma unroll
        for (int kt = 0; kt < 4; ++kt)
#pragma unroll
            for (int mt = 0; mt < 4; ++mt)
                pacc[mt] = __builtin_amdgcn_mfma_f32_16x16x32_f16(Ap[kt][mt], Bp[kt], pacc[mt], 0, 0, 0);
#pragma unroll 1
        for (int mt = 0; mt < 4; ++mt) {
            if (n16 < 8) {
#pragma unroll
                for (int r = 0; r < 4; ++r)
                    zw[(q * 4 + r) * 9 + n16] = pacc[mt][r];
            }
            if (lane < 16) {
                half8 hv;
#pragma unroll
                for (int u = 0; u < 8; ++u)
                    hv[u] = (_Float16)fmaxf(zw[lane * 9 + u] + bh[u], 0.f);
                const int mtg = w * 4 + mt;
                *(half8*)(PFdst + ((size_t)mtg * 32 + (sp >> 2)) * 512
                          + ((sp & 3) * 16 + lane) * 8) = hv;
            }
        }
    };

    // ---- pre-phase (p = -2): proj(0) ----
    if (doProj) proj_step(0, PF[0]);
    grid_barrier(barrier_mem, 1u, xcd);

    // ---- phases p = -1 .. 257 ----
    for (int p = -1; p <= 257; ++p) {
        bool doFin = false, doStat = false;
        const _Float16 *Arec = nullptr, *Astat = nullptr;
        _Float16* hdst = nullptr;
        float* outp = nullptr;
        if (layer == 0) {
            doFin = (p >= 0 && p <= 255);
            if (doFin) { if (p > 0) Arec = H1[(p - 1) & 1]; hdst = H1[p & 1]; }
            doStat = (p >= -1 && p <= 254);
            if (doStat) Astat = PF[(p + 1) & 1];
        } else {
            const int t = p - 2;
            doFin = (p >= 2 && p <= 257);
            if (doFin) {
                if (t > 0) Arec = H2[(t - 1) & 1];
                hdst = H2[t & 1];
                outp = (t == 255) ? out : nullptr;
            }
            doStat = (p >= 1 && p <= 256);
            if (doStat) Astat = H1[(p - 1) & 1];
        }

        if (doFin && Arec) { pipe_issue(Arec); pipe_run(Arec, 32768); } // rec half
        if (doStat) pipe_issue(Astat);          // static loads fly under epilogue
        if (doFin) epilogue(hdst, outp);
        if (doStat) { zero_acc(); pipe_run(Astat, 0); }  // static half -> acc2
        if (doProj && p <= 253) proj_step(p + 2, PF[p & 1]);

        grid_barrier(barrier_mem, (uint32_t)(p + 3), xcd);
    }
#undef ISSUE2
#undef WAITG
#undef MFMA2G
}

// ---------------------------------------------------------------------------
extern "C" void kernel_launch(void* const* d_in, const int* in_sizes, int n_in,
                              void* d_out, int out_size, void* d_ws, size_t ws_size,
                              hipStream_t stream)
{
    const float* x   = (const float*)d_in[0];
    const float* W_h = (const float*)d_in[1];
    const float* b_h = (const float*)d_in[2];
    const float* k1  = (const float*)d_in[3];
    const float* b1  = (const float*)d_in[4];
    const float* k2  = (const float*)d_in[5];
    const float* b2  = (const float*)d_in[6];
    float* out = (float*)d_out;

    const size_t MB = 1024 * 1024;
    uint8_t* wsb = (uint8_t*)d_ws;
    // 0-6 MB: PF[2],H1[2],H2[2] (1 MB each) ; xf 8-40 MB ; barrier @44 MB
    _Float16* xf = (_Float16*)(wsb + 8 * MB);
    uint32_t* barrier_mem = (uint32_t*)(wsb + 44 * MB);

    hipFuncSetAttribute((const void*)persist_kernel,
                        hipFuncAttributeMaxDynamicSharedMemorySize, SMEM_BYTES);

    hipMemsetAsync(wsb, 0, 6 * MB, stream);
    hipMemsetAsync(barrier_mem, 0, 4096, stream);
    xconv_kernel<<<dim3(32, 16), 256, 0, stream>>>(x, xf);
    persist_kernel<<<NWGS, 512, SMEM_BYTES, stream>>>(
        k1, b1, k2, b2, W_h, b_h, xf, wsb, out, barrier_mem);
}

// Round 7
// 9634.080 us; speedup vs baseline: 1.0678x; 1.0122x over previous
//
#include <hip/hip_runtime.h>
#include <cstddef>
#include <cstdint>

#define T_STEPS 256
#define BATCH   512
#define NIN     128
#define NHID    1024
#define NWGS    256

typedef _Float16 half8  __attribute__((ext_vector_type(8)));
typedef float    float4v __attribute__((ext_vector_type(4)));

__device__ __forceinline__ float sigmoid_f(float x) { return 1.0f / (1.0f + __expf(-x)); }
__device__ __forceinline__ float tanh_f(float x) {
    float ax = fabsf(x);
    float t  = __expf(-2.0f * ax);
    float r  = (1.0f - t) / (1.0f + t);
    return copysignf(r, x);
}

// LDS map: double-buffered A+B staging (2 x 64 KB) + proj weights + biases.
// Epilogue scratch (zw 8x4352B, hs 8x512B) OVERLAYS buf[0] (dead by then).
#define STG_OFF   0         // 131072 B: buf[2]: [A: kt4][mt8][1KB] ++ [B: kt4][nt8][1KB]
#define WHF_OFF   131072    // 4096 B: proj B-frags [kt 4][lane 64][16B]
#define BIASG_OFF 135168    // 512 B: gate bias [g 4][u 32] f32
#define BH_OFF    135680    // 32 B: proj bias [u 8] f32
#define SMEM_BYTES 135712

#define GL_LDS(g, l) __builtin_amdgcn_global_load_lds( \
    (const __attribute__((address_space(1))) uint32_t*)(g), \
    (__attribute__((address_space(3))) uint32_t*)(l), 16, 0, 0)

// ---------------------------------------------------------------------------
// Tree grid barrier (proven): 8 sub-counters fan into master -> gen.
// Layout (uint32 idx): sub[g] at g*32, master at 256, gen at 320.
// ---------------------------------------------------------------------------
__device__ __forceinline__ void grid_barrier(uint32_t* bm, uint32_t target_gen,
                                             int grp) {
    __syncthreads();
    if (threadIdx.x == 0) {
        __threadfence();
        uint32_t old = __hip_atomic_fetch_add(bm + grp * 32, 1u, __ATOMIC_RELAXED,
                                              __HIP_MEMORY_SCOPE_AGENT);
        if (old == target_gen * 32u - 1u) {
            uint32_t mold = __hip_atomic_fetch_add(bm + 256, 1u, __ATOMIC_RELAXED,
                                                   __HIP_MEMORY_SCOPE_AGENT);
            if (mold == target_gen * 8u - 1u)
                __hip_atomic_store(bm + 320, target_gen, __ATOMIC_RELAXED,
                                   __HIP_MEMORY_SCOPE_AGENT);
        }
        uint32_t spins = 0;
        while (__hip_atomic_load(bm + 320, __ATOMIC_RELAXED,
                                 __HIP_MEMORY_SCOPE_AGENT) < target_gen) {
            __builtin_amdgcn_s_sleep(8);
            if (++spins > 20000000u) break;
        }
        __threadfence();
    }
    __syncthreads();
}

// ---------------------------------------------------------------------------
// One-time x -> fp16 A-frag conversion (unchanged, proven).
// xf[t 256][mt 32][kt 4][512 halves]
// ---------------------------------------------------------------------------
__global__ __launch_bounds__(256)
void xconv_kernel(const float* __restrict__ x, _Float16* __restrict__ xf)
{
    __shared__ float xs[16][2][128];
    const int mt = blockIdx.x, tb = blockIdx.y;
    const int t = threadIdx.x;
    for (int tl = 0; tl < 8; ++tl) {
        __syncthreads();
#pragma unroll
        for (int i = 0; i < 4; ++i) {
            const int idx = t + i * 256;
            const int m = idx >> 6, rest = idx & 63;
            const int t2 = rest >> 5, k4 = rest & 31;
            float4v v = *(const float4v*)(x +
                ((size_t)(mt * 16 + m) * T_STEPS + (tb * 16 + tl * 2 + t2)) * NIN + k4 * 4);
            *(float4v*)&xs[m][t2][k4 * 4] = v;
        }
        __syncthreads();
#pragma unroll
        for (int i = 0; i < 2; ++i) {
            const int idx = t + i * 256;
            const int t2 = idx >> 8, rest = idx & 255;
            const int kt = rest >> 6, lane = rest & 63;
            half8 hv;
#pragma unroll
            for (int j = 0; j < 8; ++j)
                hv[j] = (_Float16)xs[lane & 15][t2][kt * 32 + (lane >> 4) * 8 + j];
            const int tg = tb * 16 + tl * 2 + t2;
            *(half8*)(xf + (((size_t)tg * 32 + mt) * 4 + kt) * 512 + lane * 8) = hv;
        }
    }
}

// ---------------------------------------------------------------------------
// One-time weight f32 -> f16 frag conversion.
// wf[layer 2][uc 32][kt 64][nt 8][512 halves]:
//   value(l,j) = W[kt*32 + (l>>4)*8 + j][g*1024 + uc*32 + wn*16 + (l&15)]
//   where g = nt>>1, wn = nt&1. 64 blocks x 256 thr.
// ---------------------------------------------------------------------------
__global__ __launch_bounds__(256)
void wconv_kernel(const float* __restrict__ k1, const float* __restrict__ k2,
                  _Float16* __restrict__ wf)
{
    const int b = blockIdx.x;
    const int layer = b >> 5, uc = b & 31;
    const float* W = layer ? k2 : k1;
    _Float16* dst = wf + (size_t)(layer * 32 + uc) * 512 * 512;
    for (int it = threadIdx.x; it < 64 * 8 * 64; it += 256) {
        const int l = it & 63, nt = (it >> 6) & 7, kt = it >> 9;
        const int g = nt >> 1, wn = nt & 1;
        const int col = g * 1024 + uc * 32 + wn * 16 + (l & 15);
        const int krow = kt * 32 + ((l >> 4) * 8);
        half8 hv;
#pragma unroll
        for (int j = 0; j < 8; ++j)
            hv[j] = (_Float16)W[(size_t)(krow + j) * 4096 + col];
        *(half8*)(dst + ((size_t)(kt * 8 + nt) * 64 + l) * 8) = hv;
    }
}

// ---------------------------------------------------------------------------
// Persistent kernel, 128x128 TILES. 256 WGs x 512 thr, 1 WG/CU.
// xcd = bid&7: layer = xcd>>2, rm = xcd&3 (row-tile, 128 rows); uc = bid>>3
// (unit-col tile, 32 units x 4 gates = 128 cols). K = 2048 (lo 32 kt = pf/h1,
// hi 32 kt = h1/h2), 16 chunks of 4 kt; A+B staged via global_load_lds with
// counted vmcnt(8) (T3/T4: never drain mid-loop). Per-WG LLC read = 1 MB/phase
// (A 512K + B 512K) -> chip 256 MB/phase vs old 512 MB.
// Waves: w = mp*2+wn (mp 0..3: 2 mt = 32 rows; wn 0..1: 16 units, all gates).
// ---------------------------------------------------------------------------
__global__ __launch_bounds__(512, 2)
void persist_kernel(const float* __restrict__ b1, const float* __restrict__ b2,
                    const float* __restrict__ W_h, const float* __restrict__ b_h,
                    const _Float16* __restrict__ xf,
                    const _Float16* __restrict__ wf,
                    uint8_t* wsb, float* __restrict__ out,
                    uint32_t* barrier_mem)
{
    extern __shared__ __align__(16) char smem[];
    const size_t MB = 1024 * 1024;
    _Float16* PF[2] = {(_Float16*)(wsb + 0 * MB), (_Float16*)(wsb + 1 * MB)};
    _Float16* H1[2] = {(_Float16*)(wsb + 2 * MB), (_Float16*)(wsb + 3 * MB)};
    _Float16* H2[2] = {(_Float16*)(wsb + 4 * MB), (_Float16*)(wsb + 5 * MB)};

    const int tid = threadIdx.x;
    const int w = tid >> 6, lane = tid & 63;
    const int q = lane >> 4, n16 = lane & 15;
    const int mp = w >> 1, wn = w & 1;
    const int bid = blockIdx.x;
    const int xcd = bid & 7;
    const int layer = xcd >> 2;
    const int rm = xcd & 3;              // row-tile 0..3 (128 rows each)
    const int uc = bid >> 3;             // unit-col tile 0..31 (32 units)
    const bool doProj = (rm < 2);
    const int sp = (layer * 2 + rm) * 32 + uc;   // proj slice 0..127
    const int pu0 = sp * 8;

    const float* bsrc = layer ? b2 : b1;

    // ---- init: biases + proj weights ----
    if (tid < 128)
        ((float*)(smem + BIASG_OFF))[tid] =
            bsrc[(tid >> 5) * 1024 + uc * 32 + (tid & 31)];
    if (doProj) {
        if (tid < 256) {
            const int kt = tid >> 6, ln = tid & 63;
            const int nn = ln & 15;
            half8 hv;
#pragma unroll
            for (int j = 0; j < 8; ++j) {
                float v = (nn < 8)
                    ? W_h[(size_t)(kt * 32 + (ln >> 4) * 8 + j) * NHID + pu0 + nn] : 0.f;
                hv[j] = (_Float16)v;
            }
            *(half8*)(smem + WHF_OFF + kt * 1024 + ln * 16) = hv;
        }
        if (tid < 8) ((float*)(smem + BH_OFF))[tid] = b_h[pu0 + tid];
    }
    __syncthreads();

    const float* bg = (const float*)(smem + BIASG_OFF);
    const float* bh = (const float*)(smem + BH_OFF);
    float* zwv = (float*)(smem + (size_t)w * 4352);          // overlay in buf[0]
    _Float16* hs = (_Float16*)(smem + 34816 + w * 512);      // overlay in buf[0]

    const _Float16* wslice = wf + (size_t)(layer * 32 + uc) * 512 * 512;

    // c-state: lane owns (row = n16 of each of 2 mts, units q*4..q*4+3)
    float cst[2][4];
#pragma unroll
    for (int am = 0; am < 2; ++am)
#pragma unroll
        for (int uu = 0; uu < 4; ++uu) cst[am][uu] = 0.f;

    // ---- stage one chunk (4 kt): 4 A frags (mt=w) + 4 B frags (nt=w) ----
    auto stage_chunk = [&](int c, const _Float16* Alo, const _Float16* Ahi) {
        const _Float16* As = (c < 8) ? Alo : Ahi;
        const int ktl = (c * 4) & 31;
        char* dst = smem + STG_OFF + (c & 1) * 65536;
#pragma unroll
        for (int k = 0; k < 4; ++k) {
            const _Float16* ga = As +
                ((size_t)(rm * 8 + w) * 32 + ktl + k) * 512 + lane * 8;
            GL_LDS(ga, dst + (k * 8 + w) * 1024);
            const _Float16* gb = wslice +
                ((size_t)((c * 4 + k) * 8 + w)) * 512 + lane * 8;
            GL_LDS(gb, dst + 32768 + (k * 8 + w) * 1024);
        }
    };

    // ---- one layer-GEMM phase: 16 chunks, counted-vmcnt pipeline ----
    auto gemm_phase = [&](const _Float16* Alo, const _Float16* Ahi,
                          _Float16* hdst, float* outp) {
        float4v acc[2][4];
#pragma unroll
        for (int am = 0; am < 2; ++am)
#pragma unroll
            for (int g = 0; g < 4; ++g)
                acc[am][g] = (float4v){0.f, 0.f, 0.f, 0.f};

        stage_chunk(0, Alo, Ahi);
#pragma unroll 1
        for (int c = 0; c < 16; ++c) {
            if (c < 15) stage_chunk(c + 1, Alo, Ahi);
            __builtin_amdgcn_sched_barrier(0);
            if (c < 15) asm volatile("s_waitcnt vmcnt(8)" ::: "memory");
            else        asm volatile("s_waitcnt vmcnt(0)" ::: "memory");
            __builtin_amdgcn_s_barrier();
            __builtin_amdgcn_sched_barrier(0);
            const char* buf = smem + STG_OFF + (c & 1) * 65536;
#pragma unroll
            for (int k = 0; k < 4; ++k) {
                half8 Af0 = *(const half8*)(buf + (k * 8 + mp * 2 + 0) * 1024 + lane * 16);
                half8 Af1 = *(const half8*)(buf + (k * 8 + mp * 2 + 1) * 1024 + lane * 16);
#pragma unroll
                for (int g = 0; g < 4; ++g) {
                    half8 Bf = *(const half8*)(buf + 32768
                                 + (k * 8 + g * 2 + wn) * 1024 + lane * 16);
                    acc[0][g] = __builtin_amdgcn_mfma_f32_16x16x32_f16(Af0, Bf, acc[0][g], 0, 0, 0);
                    acc[1][g] = __builtin_amdgcn_mfma_f32_16x16x32_f16(Af1, Bf, acc[1][g], 0, 0, 0);
                }
            }
        }

        // ---- epilogue: per mt transpose via zw, LSTM gates, h-frag write ----
#pragma unroll 1
        for (int am = 0; am < 2; ++am) {
#pragma unroll
            for (int g = 0; g < 4; ++g)
#pragma unroll
                for (int r = 0; r < 4; ++r)
                    zwv[(q * 4 + r) * 68 + g * 17 + n16] = acc[am][g][r];
#pragma unroll
            for (int uu = 0; uu < 4; ++uu) {
                const int ul = wn * 16 + q * 4 + uu;     // unit local in 32
                const float zi = zwv[n16 * 68 +  0 + q * 4 + uu] + bg[ul];
                const float zj = zwv[n16 * 68 + 17 + q * 4 + uu] + bg[32 + ul];
                const float zf = zwv[n16 * 68 + 34 + q * 4 + uu] + bg[64 + ul];
                const float zo = zwv[n16 * 68 + 51 + q * 4 + uu] + bg[96 + ul];
                float c = cst[am][uu] * sigmoid_f(zf + 1.0f)
                        + sigmoid_f(zi) * tanh_f(zj);
                cst[am][uu] = c;
                const float h = tanh_f(c) * sigmoid_f(zo);
                hs[n16 * 16 + q * 4 + uu] = (_Float16)h;
                if (outp)
                    outp[(size_t)(rm * 128 + (mp * 2 + am) * 16 + n16) * NHID
                         + uc * 32 + ul] = h;
            }
            if (lane < 32) {   // wave-internal DS (in-order per wave)
                half8 hv = *(half8*)(hs + (lane & 15) * 16 + (lane >> 4) * 8);
                *(half8*)((char*)hdst
                    + ((size_t)(rm * 8 + mp * 2 + am) * 32 + uc) * 1024
                    + (wn * 32 + lane) * 16) = hv;
            }
        }
    };

    // ---- proj (rm<2 WGs): pf(tstep), M=512 x 8 units, K=128 ----
    auto proj_step = [&](int tstep, _Float16* PFdst) {
        float4v pacc[4];
#pragma unroll
        for (int mt = 0; mt < 4; ++mt) pacc[mt] = (float4v){0.f, 0.f, 0.f, 0.f};
        half8 Bp[4], Ap[4][4];
#pragma unroll
        for (int kt = 0; kt < 4; ++kt) {
            Bp[kt] = *(const half8*)(smem + WHF_OFF + kt * 1024 + lane * 16);
#pragma unroll
            for (int mt = 0; mt < 4; ++mt)
                Ap[kt][mt] = *(const half8*)(xf +
                    (((size_t)tstep * 32 + (w * 4 + mt)) * 4 + kt) * 512 + lane * 8);
        }
#pragma unroll
        for (int kt = 0; kt < 4; ++kt)
#pragma unroll
            for (int mt = 0; mt < 4; ++mt)
                pacc[mt] = __builtin_amdgcn_mfma_f32_16x16x32_f16(Ap[kt][mt], Bp[kt], pacc[mt], 0, 0, 0);
#pragma unroll 1
        for (int mt = 0; mt < 4; ++mt) {
            if (n16 < 8) {
#pragma unroll
                for (int r = 0; r < 4; ++r)
                    zwv[(q * 4 + r) * 9 + n16] = pacc[mt][r];
            }
            if (lane < 16) {
                half8 hv;
#pragma unroll
                for (int u = 0; u < 8; ++u)
                    hv[u] = (_Float16)fmaxf(zwv[lane * 9 + u] + bh[u], 0.f);
                const int mtg = w * 4 + mt;
                *(half8*)(PFdst + ((size_t)mtg * 32 + (sp >> 2)) * 512
                          + ((sp & 3) * 16 + lane) * 8) = hv;
            }
        }
    };

    // ---- pre-phase: proj(0) -> PF[0] ----
    if (doProj) proj_step(0, PF[0]);
    grid_barrier(barrier_mem, 1u, xcd);

    // ---- phases p = 0..256 ----
    for (int p = 0; p <= 256; ++p) {
        if (layer == 0) {
            if (p <= 255)
                gemm_phase(PF[p & 1], H1[(p + 1) & 1], H1[p & 1], nullptr);
        } else {
            if (p >= 1) {
                const int t = p - 1;
                gemm_phase(H1[t & 1], H2[(t + 1) & 1], H2[t & 1],
                           (t == 255) ? out : nullptr);
            }
        }
        if (doProj && p <= 254) proj_step(p + 1, PF[(p + 1) & 1]);
        grid_barrier(barrier_mem, (uint32_t)(p + 2), xcd);
    }
}

// ---------------------------------------------------------------------------
extern "C" void kernel_launch(void* const* d_in, const int* in_sizes, int n_in,
                              void* d_out, int out_size, void* d_ws, size_t ws_size,
                              hipStream_t stream)
{
    const float* x   = (const float*)d_in[0];
    const float* W_h = (const float*)d_in[1];
    const float* b_h = (const float*)d_in[2];
    const float* k1  = (const float*)d_in[3];
    const float* b1  = (const float*)d_in[4];
    const float* k2  = (const float*)d_in[5];
    const float* b2  = (const float*)d_in[6];
    float* out = (float*)d_out;

    const size_t MB = 1024 * 1024;
    uint8_t* wsb = (uint8_t*)d_ws;
    // 0-6 MB: PF[2],H1[2],H2[2] (1 MB each, zeroed)
    // 6-38 MB: wf (f16 weight frags, 2 layers x 16 MB)
    // 38-70 MB: xf ; barrier @ 70 MB
    _Float16* wf = (_Float16*)(wsb + 6 * MB);
    _Float16* xf = (_Float16*)(wsb + 38 * MB);
    uint32_t* barrier_mem = (uint32_t*)(wsb + 70 * MB);

    hipFuncSetAttribute((const void*)persist_kernel,
                        hipFuncAttributeMaxDynamicSharedMemorySize, SMEM_BYTES);

    hipMemsetAsync(wsb, 0, 6 * MB, stream);
    hipMemsetAsync(barrier_mem, 0, 4096, stream);
    wconv_kernel<<<64, 256, 0, stream>>>(k1, k2, wf);
    xconv_kernel<<<dim3(32, 16), 256, 0, stream>>>(x, xf);
    persist_kernel<<<NWGS, 512, SMEM_BYTES, stream>>>(
        b1, b2, W_h, b_h, xf, wf, wsb, out, barrier_mem);
}

// Round 8
// 7537.984 us; speedup vs baseline: 1.3647x; 1.2781x over previous
//
#include <hip/hip_runtime.h>
#include <cstddef>
#include <cstdint>

#define T_STEPS 256
#define BATCH   512
#define NIN     128
#define NHID    1024
#define NWGS    256

typedef _Float16 half8  __attribute__((ext_vector_type(8)));
typedef float    float4v __attribute__((ext_vector_type(4)));
typedef float    float2v __attribute__((ext_vector_type(2)));

__device__ __forceinline__ float sigmoid_f(float x) { return 1.0f / (1.0f + __expf(-x)); }
__device__ __forceinline__ float tanh_f(float x) {
    float ax = fabsf(x);
    float t  = __expf(-2.0f * ax);
    float r  = (1.0f - t) / (1.0f + t);
    return copysignf(r, x);
}

// Write-through store (sc0 sc1): data goes to the coherence point (LLC),
// leaves NO dirty L2 line -> release fence needs no buffer_wbl2 walk.
#define STORE_SC(addr, val)                                                     \
    asm volatile("global_store_dwordx4 %0, %1, off sc0 sc1"                     \
                 :: "v"((const void*)(addr)), "v"(val) : "memory")

// LDS map (identical to R4's proven map)
#define WLDS_OFF  0         // 131072 B: weight B-frags [nt 2][kt 64][lane 64][16B]
#define WHF_OFF   131072    // 4096 B:  proj B-frags [kt 4][lane 64][16B]
#define ZS_OFF    135168    // 18432 B: per-wave z scratch (2304 B each, 16 rows x 36 f32)
#define ZW_BYTES  2304
#define HS_OFF    153600    // 2048 B:  per-wave h scratch (256 B each)
#define BIASG_OFF 155648    // 128 B:   gate bias [g 4][u 8] f32
#define BH_OFF    155776    // 32 B:    proj bias [u 8] f32
#define SMEM_BYTES 155808

// ---------------------------------------------------------------------------
// LITE tree grid barrier: no __threadfence.
// Release: hipcc's __syncthreads drains each wave's vmcnt, and all cross-WG
// data stores are sc0/sc1 write-through -> already at LLC when we arrive.
// Acquire: single ACQUIRE atomic load (buffer_inv only, no wbl2 walk).
// Layout (uint32 idx): sub[g] at g*32, master at 256, gen at 320.
// ---------------------------------------------------------------------------
__device__ __forceinline__ void grid_barrier(uint32_t* bm, uint32_t target_gen,
                                             int grp) {
    __syncthreads();    // compiler emits s_waitcnt vmcnt(0) before s_barrier
    if (threadIdx.x == 0) {
        uint32_t old = __hip_atomic_fetch_add(bm + grp * 32, 1u, __ATOMIC_RELAXED,
                                              __HIP_MEMORY_SCOPE_AGENT);
        if (old == target_gen * 32u - 1u) {
            uint32_t mold = __hip_atomic_fetch_add(bm + 256, 1u, __ATOMIC_RELAXED,
                                                   __HIP_MEMORY_SCOPE_AGENT);
            if (mold == target_gen * 8u - 1u)
                __hip_atomic_store(bm + 320, target_gen, __ATOMIC_RELAXED,
                                   __HIP_MEMORY_SCOPE_AGENT);
        }
        uint32_t spins = 0;
        while (__hip_atomic_load(bm + 320, __ATOMIC_RELAXED,
                                 __HIP_MEMORY_SCOPE_AGENT) < target_gen) {
            __builtin_amdgcn_s_sleep(8);
            if (++spins > 20000000u) break;
        }
        // acquire: invalidate L1 + XCD L2 so A-buffer reads refill from LLC
        (void)__hip_atomic_load(bm + 320, __ATOMIC_ACQUIRE,
                                __HIP_MEMORY_SCOPE_AGENT);
    }
    __syncthreads();
}

// ---------------------------------------------------------------------------
// One-time x -> fp16 A-frag conversion (unchanged, proven).
// xf[t 256][mt 32][kt 4][512 halves]
// ---------------------------------------------------------------------------
__global__ __launch_bounds__(256)
void xconv_kernel(const float* __restrict__ x, _Float16* __restrict__ xf)
{
    __shared__ float xs[16][2][128];
    const int mt = blockIdx.x, tb = blockIdx.y;
    const int t = threadIdx.x;
    for (int tl = 0; tl < 8; ++tl) {
        __syncthreads();
#pragma unroll
        for (int i = 0; i < 4; ++i) {
            const int idx = t + i * 256;
            const int m = idx >> 6, rest = idx & 63;
            const int t2 = rest >> 5, k4 = rest & 31;
            float4v v = *(const float4v*)(x +
                ((size_t)(mt * 16 + m) * T_STEPS + (tb * 16 + tl * 2 + t2)) * NIN + k4 * 4);
            *(float4v*)&xs[m][t2][k4 * 4] = v;
        }
        __syncthreads();
#pragma unroll
        for (int i = 0; i < 2; ++i) {
            const int idx = t + i * 256;
            const int t2 = idx >> 8, rest = idx & 255;
            const int kt = rest >> 6, lane = rest & 63;
            half8 hv;
#pragma unroll
            for (int j = 0; j < 8; ++j)
                hv[j] = (_Float16)xs[lane & 15][t2][kt * 32 + (lane >> 4) * 8 + j];
            const int tg = tb * 16 + tl * 2 + t2;
            *(half8*)(xf + (((size_t)tg * 32 + mt) * 4 + kt) * 512 + lane * 8) = hv;
        }
    }
}

// ---------------------------------------------------------------------------
// Persistent kernel (R4 structure + lite barrier + sc stores + balanced proj).
// 256 WGs x 512 thr, 1 WG/CU (152 KB LDS).
// xcd = bid&7; layer = xcd>>2; s = (xcd&3)*32 + (bid>>3); u0 = s*8.
// GEMM K-loop: depth-3 counted-vmcnt inline-asm pipeline (proven R4).
// proj: ALL WGs, 2 mt each (mt-half = layer) -> no straggler at the barrier.
// ---------------------------------------------------------------------------
__global__ __launch_bounds__(512, 2)
void persist_kernel(const float* __restrict__ k1, const float* __restrict__ b1,
                    const float* __restrict__ k2, const float* __restrict__ b2,
                    const float* __restrict__ W_h, const float* __restrict__ b_h,
                    const _Float16* __restrict__ xf,
                    uint8_t* wsb, float* __restrict__ out,
                    uint32_t* barrier_mem)
{
    extern __shared__ __align__(16) char smem[];
    const size_t MB = 1024 * 1024;
    _Float16* A1b[2] = {(_Float16*)(wsb + 0 * MB), (_Float16*)(wsb + 2 * MB)};
    _Float16* A2b[2] = {(_Float16*)(wsb + 4 * MB), (_Float16*)(wsb + 6 * MB)};

    const int tid = threadIdx.x;
    const int w = tid >> 6, lane = tid & 63;
    const int q = lane >> 4, n16 = lane & 15;
    const int bid = blockIdx.x;
    const int xcd = bid & 7;
    const int layer = xcd >> 2;              // XCDs 0-3: layer 0; 4-7: layer 1
    const int s = (xcd & 3) * 32 + (bid >> 3);   // 0..127, bijective per layer
    const int u0 = s * 8;
    const int pu0 = s * 8;                   // proj slice s, shared by both layers

    const float* ksrc = layer ? k2 : k1;
    const float* bsrc = layer ? b2 : b1;

    // ---- init: convert weight slice f32 -> fp16 frags in LDS (R4 verbatim) ----
    {
#pragma unroll 1
        for (int i = 0; i < 16; ++i) {
            const int kt = w * 8 + (i & 7);
            const int nt = i >> 3;
            const int colg = (nt * 2 + (n16 >> 3)) * 1024 + u0 + (n16 & 7);
            half8 hv;
#pragma unroll
            for (int j = 0; j < 8; ++j)
                hv[j] = (_Float16)ksrc[(size_t)(kt * 32 + q * 8 + j) * 4096 + colg];
            *(half8*)(smem + WLDS_OFF + (nt * 64 + kt) * 1024 + lane * 16) = hv;
        }
    }
    if (tid < 32)
        ((float*)(smem + BIASG_OFF))[tid] = bsrc[(tid >> 3) * 1024 + u0 + (tid & 7)];
    {   // proj weights: ALL WGs now (slice s, both layers load the same slice)
        if (tid < 256) {
            const int kt = tid >> 6, ln = tid & 63;
            const int nn = ln & 15;
            half8 hv;
#pragma unroll
            for (int j = 0; j < 8; ++j) {
                float v = (nn < 8)
                    ? W_h[(size_t)(kt * 32 + (ln >> 4) * 8 + j) * NHID + pu0 + nn] : 0.f;
                hv[j] = (_Float16)v;
            }
            *(half8*)(smem + WHF_OFF + kt * 1024 + ln * 16) = hv;
        }
        if (tid < 8) ((float*)(smem + BH_OFF))[tid] = b_h[pu0 + tid];
    }
    __syncthreads();

    const float* bg = (const float*)(smem + BIASG_OFF);
    const float* bh = (const float*)(smem + BH_OFF);
    float* zw = (float*)(smem + ZS_OFF + w * ZW_BYTES);     // [16 rows][36 f32]
    _Float16* hw = (_Float16*)(smem + HS_OFF + w * 256);    // [16 rows][8 u]

    // c state: lane owns (row = n16, units q*2, q*2+1) per mt
    float cst[4][2];
#pragma unroll
    for (int mt = 0; mt < 4; ++mt) { cst[mt][0] = 0.f; cst[mt][1] = 0.f; }

    // ---- proj body (ALL WGs, 2 mt each; mt-half = layer): pf(t) -> A1 low ----
    auto proj_step = [&](int tstep, _Float16* A1dst) {
        float4v pacc[2];
#pragma unroll
        for (int mi = 0; mi < 2; ++mi) pacc[mi] = (float4v){0.f, 0.f, 0.f, 0.f};
        half8 Bp[4];
        half8 Ap[4][2];
#pragma unroll
        for (int kt = 0; kt < 4; ++kt) {
            Bp[kt] = *(const half8*)(smem + WHF_OFF + kt * 1024 + lane * 16);
#pragma unroll
            for (int mi = 0; mi < 2; ++mi)
                Ap[kt][mi] = *(const half8*)(xf +
                    (((size_t)tstep * 32 + (w * 4 + layer * 2 + mi)) * 4 + kt) * 512
                    + lane * 8);
        }
#pragma unroll
        for (int kt = 0; kt < 4; ++kt)
#pragma unroll
            for (int mi = 0; mi < 2; ++mi)
                pacc[mi] = __builtin_amdgcn_mfma_f32_16x16x32_f16(Ap[kt][mi], Bp[kt], pacc[mi], 0, 0, 0);
#pragma unroll 1
        for (int mi = 0; mi < 2; ++mi) {
            if (n16 < 8) {
#pragma unroll
                for (int r = 0; r < 4; ++r)
                    zw[(q * 4 + r) * 9 + n16] = pacc[mi][r];   // stride 9: conflict-free
            }
            if (lane < 16) {
                half8 hv;
#pragma unroll
                for (int u = 0; u < 8; ++u)
                    hv[u] = (_Float16)fmaxf(zw[lane * 9 + u] + bh[u], 0.f);
                const int mtg = w * 4 + layer * 2 + mi;
                _Float16* dst = A1dst + ((size_t)mtg * 64 + (s >> 2)) * 512
                                + ((s & 3) * 16 + lane) * 8;
                STORE_SC(dst, hv);
            }
        }
    };

    // ---- LSTM GEMM + fused epilogue; depth-3 counted-vmcnt asm pipeline ----
    auto gemm_step = [&](const _Float16* Asrc, _Float16* hdst1, _Float16* hdst2,
                         float* outp) {
        float4v acc[4][2];
#pragma unroll
        for (int mt = 0; mt < 4; ++mt) {
            acc[mt][0] = (float4v){0.f, 0.f, 0.f, 0.f};
            acc[mt][1] = (float4v){0.f, 0.f, 0.f, 0.f};
        }
        const char* aw[4];
#pragma unroll
        for (int mt = 0; mt < 4; ++mt)
            aw[mt] = (const char*)Asrc + ((size_t)(w * 4 + mt) * 64) * 1024 + lane * 16;

        half8 G0[8], G1[8], G2[8];   // 3 groups x 2 kt x 4 mt, static indexing

#define ISSUE2(buf, kb)                                                         \
        do {                                                                    \
            _Pragma("unroll")                                                   \
            for (int kk = 0; kk < 2; ++kk) {                                    \
                _Pragma("unroll")                                               \
                for (int mt = 0; mt < 4; ++mt)                                  \
                    asm volatile("global_load_dwordx4 %0, %1, off"              \
                                 : "=&v"(buf[kk * 4 + mt])                      \
                                 : "v"(aw[mt] + (size_t)((kb) + kk) * 1024));   \
            }                                                                   \
        } while (0)

#define WAITG(n, buf)                                                           \
        do {                                                                    \
            asm volatile("s_waitcnt vmcnt(" #n ")"                              \
                : "+v"(buf[0]), "+v"(buf[1]), "+v"(buf[2]), "+v"(buf[3]),       \
                  "+v"(buf[4]), "+v"(buf[5]), "+v"(buf[6]), "+v"(buf[7]));      \
            __builtin_amdgcn_sched_barrier(0);                                  \
        } while (0)

#define MFMA2(buf, kb)                                                          \
        do {                                                                    \
            _Pragma("unroll")                                                   \
            for (int kk = 0; kk < 2; ++kk) {                                    \
                half8 B0 = *(const half8*)(smem + WLDS_OFF                      \
                              + (size_t)((kb) + kk) * 1024 + lane * 16);        \
                half8 B1 = *(const half8*)(smem + WLDS_OFF + 65536              \
                              + (size_t)((kb) + kk) * 1024 + lane * 16);        \
                _Pragma("unroll")                                               \
                for (int mt = 0; mt < 4; ++mt)                                  \
                    acc[mt][0] = __builtin_amdgcn_mfma_f32_16x16x32_f16(        \
                        buf[kk * 4 + mt], B0, acc[mt][0], 0, 0, 0);             \
                _Pragma("unroll")                                               \
                for (int mt = 0; mt < 4; ++mt)                                  \
                    acc[mt][1] = __builtin_amdgcn_mfma_f32_16x16x32_f16(        \
                        buf[kk * 4 + mt], B1, acc[mt][1], 0, 0, 0);             \
            }                                                                   \
        } while (0)

        ISSUE2(G0, 0);
        ISSUE2(G1, 2);
        ISSUE2(G2, 4);               // 24 outstanding
#pragma unroll 1
        for (int g3 = 0; g3 < 10; ++g3) {
            const int kb = g3 * 6;
            WAITG(16, G0);  MFMA2(G0, kb);      ISSUE2(G0, kb + 6);
            WAITG(16, G1);  MFMA2(G1, kb + 2);  ISSUE2(G1, kb + 8);
            WAITG(16, G2);  MFMA2(G2, kb + 4);
            if (g3 < 9) ISSUE2(G2, kb + 10);
        }
        // tail: G0 holds kt 60, G1 holds kt 62; 16 outstanding
        WAITG(8, G0);
        MFMA2(G0, 60);
        WAITG(0, G1);
        MFMA2(G1, 62);
#undef ISSUE2
#undef WAITG
#undef MFMA2

        // epilogue per mt (cols: g*8+u), zw stride 36
#pragma unroll 1
        for (int mt = 0; mt < 4; ++mt) {
#pragma unroll
            for (int nt = 0; nt < 2; ++nt)
#pragma unroll
                for (int r = 0; r < 4; ++r)
                    zw[(q * 4 + r) * 36 + nt * 16 + n16] = acc[mt][nt][r];
            const float* zr = zw + n16 * 36 + q * 2;
            float2v vi = *(const float2v*)(zr + 0);
            float2v vj = *(const float2v*)(zr + 8);
            float2v vf = *(const float2v*)(zr + 16);
            float2v vo = *(const float2v*)(zr + 24);
            float hvals[2];
#pragma unroll
            for (int uu = 0; uu < 2; ++uu) {
                const int u = q * 2 + uu;
                const float zi = vi[uu] + bg[u];
                const float zj = vj[uu] + bg[8 + u];
                const float zf = vf[uu] + bg[16 + u];
                const float zo = vo[uu] + bg[24 + u];
                float c = cst[mt][uu] * sigmoid_f(zf + 1.0f) + sigmoid_f(zi) * tanh_f(zj);
                cst[mt][uu] = c;
                hvals[uu] = tanh_f(c) * sigmoid_f(zo);
            }
            hw[n16 * 8 + q * 2 + 0] = (_Float16)hvals[0];
            hw[n16 * 8 + q * 2 + 1] = (_Float16)hvals[1];
            if (outp) {
                const int row = (w * 4 + mt) * 16 + n16;
                outp[(size_t)row * NHID + u0 + q * 2 + 0] = hvals[0];
                outp[(size_t)row * NHID + u0 + q * 2 + 1] = hvals[1];
            }
            if (lane < 16) {
                half8 hv = *(half8*)(hw + lane * 8);
                const size_t loff = ((s & 3) * 16 + lane) * 8;
                const int mtg = w * 4 + mt;
                _Float16* d1 = hdst1 + ((size_t)mtg * 64 + 32 + (s >> 2)) * 512 + loff;
                STORE_SC(d1, hv);
                if (hdst2) {
                    _Float16* d2 = hdst2 + ((size_t)mtg * 64 + (s >> 2)) * 512 + loff;
                    STORE_SC(d2, hv);
                }
            }
        }
    };

    // ---- pre-phase: proj(0) -> A1[0].low (all WGs, 2 mt each) ----
    proj_step(0, A1b[0]);
    grid_barrier(barrier_mem, 1u, xcd);

    // ---- phases ----
    for (int p = 0; p <= 256; ++p) {
        const int pi = p & 1, po = pi ^ 1;
        if (layer == 0) {
            if (p <= 255)
                gemm_step(A1b[pi], A1b[po], A2b[po], nullptr);   // h1 -> A1hi, A2lo
        } else {
            if (p >= 1)
                gemm_step(A2b[pi], A2b[po], nullptr,
                          (p == 256) ? out : nullptr);           // h2 -> A2hi
        }
        if (p + 1 <= 255) proj_step(p + 1, A1b[po]);             // pf(t+1) -> A1lo
        grid_barrier(barrier_mem, (uint32_t)(p + 2), xcd);
    }
}

// ---------------------------------------------------------------------------
extern "C" void kernel_launch(void* const* d_in, const int* in_sizes, int n_in,
                              void* d_out, int out_size, void* d_ws, size_t ws_size,
                              hipStream_t stream)
{
    const float* x   = (const float*)d_in[0];
    const float* W_h = (const float*)d_in[1];
    const float* b_h = (const float*)d_in[2];
    const float* k1  = (const float*)d_in[3];
    const float* b1  = (const float*)d_in[4];
    const float* k2  = (const float*)d_in[5];
    const float* b2  = (const float*)d_in[6];
    float* out = (float*)d_out;

    const size_t MB = 1024 * 1024;
    uint8_t* wsb = (uint8_t*)d_ws;
    // A1[0] 0-2, A1[1] 2-4, A2[0] 4-6, A2[1] 6-8 MB ; xf 8-40 MB ; barrier @40 MB
    _Float16* xf = (_Float16*)(wsb + 8 * MB);
    uint32_t* barrier_mem = (uint32_t*)(wsb + 40 * MB);

    hipFuncSetAttribute((const void*)persist_kernel,
                        hipFuncAttributeMaxDynamicSharedMemorySize, SMEM_BYTES);

    hipMemsetAsync(wsb, 0, 8 * MB, stream);          // zero all A-buffers
    hipMemsetAsync(barrier_mem, 0, 4096, stream);
    xconv_kernel<<<dim3(32, 16), 256, 0, stream>>>(x, xf);
    persist_kernel<<<NWGS, 512, SMEM_BYTES, stream>>>(
        k1, b1, k2, b2, W_h, b_h, xf, wsb, out, barrier_mem);
}

// Round 9
// 7267.413 us; speedup vs baseline: 1.4155x; 1.0372x over previous
//
#include <hip/hip_runtime.h>
#include <cstddef>
#include <cstdint>

#define T_STEPS 256
#define BATCH   512
#define NIN     128
#define NHID    1024
#define NWGS    256

typedef _Float16 half8  __attribute__((ext_vector_type(8)));
typedef float    float4v __attribute__((ext_vector_type(4)));
typedef float    float2v __attribute__((ext_vector_type(2)));

__device__ __forceinline__ float sigmoid_f(float x) { return 1.0f / (1.0f + __expf(-x)); }
__device__ __forceinline__ float tanh_f(float x) {
    float ax = fabsf(x);
    float t  = __expf(-2.0f * ax);
    float r  = (1.0f - t) / (1.0f + t);
    return copysignf(r, x);
}

// Write-through store (sc0 sc1): data lands at the coherence point (LLC),
// leaves NO dirty L2 line -> no buffer_wbl2 walk needed at the barrier.
#define STORE_SC(addr, val)                                                     \
    asm volatile("global_store_dwordx4 %0, %1, off sc0 sc1"                     \
                 :: "v"((const void*)(addr)), "v"(val) : "memory")

// LDS map (R4/R8 proven)
#define WLDS_OFF  0         // 131072 B: weight B-frags [nt 2][kt 64][lane 64][16B]
#define WHF_OFF   131072    // 4096 B:  proj B-frags [kt 4][lane 64][16B]
#define ZS_OFF    135168    // 18432 B: per-wave z scratch (2304 B each, 16 rows x 36 f32)
#define ZW_BYTES  2304
#define HS_OFF    153600    // 2048 B:  per-wave h scratch (256 B each)
#define BIASG_OFF 155648    // 128 B:   gate bias [g 4][u 8] f32
#define BH_OFF    155776    // 32 B:    proj bias [u 8] f32
#define SMEM_BYTES 155808

// Unified A-buffer: per mt (32) a 96 KB stripe [pf: 0-32K | h1: 32-64K | h2: 64-96K].
// Layer-0 gemm reads bytes 0..64K (pf,h1); layer-1 reads 32K..96K (h1,h2).
#define MT_STRIDE 98304
#define H1SLOT    32768
#define H2SLOT    65536

// ---------------------------------------------------------------------------
// LITE tree grid barrier (R8 proven): no __threadfence.
// Release: __syncthreads drains vmcnt; data stores are sc0/sc1 write-through.
// Acquire: single ACQUIRE atomic load (inv only, no wbl2 walk).
// Layout (uint32 idx): sub[g] at g*32, master at 256, gen at 320.
// ---------------------------------------------------------------------------
__device__ __forceinline__ void grid_barrier(uint32_t* bm, uint32_t target_gen,
                                             int grp) {
    __syncthreads();
    if (threadIdx.x == 0) {
        uint32_t old = __hip_atomic_fetch_add(bm + grp * 32, 1u, __ATOMIC_RELAXED,
                                              __HIP_MEMORY_SCOPE_AGENT);
        if (old == target_gen * 32u - 1u) {
            uint32_t mold = __hip_atomic_fetch_add(bm + 256, 1u, __ATOMIC_RELAXED,
                                                   __HIP_MEMORY_SCOPE_AGENT);
            if (mold == target_gen * 8u - 1u)
                __hip_atomic_store(bm + 320, target_gen, __ATOMIC_RELAXED,
                                   __HIP_MEMORY_SCOPE_AGENT);
        }
        uint32_t spins = 0;
        while (__hip_atomic_load(bm + 320, __ATOMIC_RELAXED,
                                 __HIP_MEMORY_SCOPE_AGENT) < target_gen) {
            __builtin_amdgcn_s_sleep(8);
            if (++spins > 20000000u) break;
        }
        (void)__hip_atomic_load(bm + 320, __ATOMIC_ACQUIRE,
                                __HIP_MEMORY_SCOPE_AGENT);
    }
    __syncthreads();
}

// ---------------------------------------------------------------------------
// One-time x -> fp16 A-frag conversion (unchanged, proven).
// xf[t 256][mt 32][kt 4][512 halves]
// ---------------------------------------------------------------------------
__global__ __launch_bounds__(256)
void xconv_kernel(const float* __restrict__ x, _Float16* __restrict__ xf)
{
    __shared__ float xs[16][2][128];
    const int mt = blockIdx.x, tb = blockIdx.y;
    const int t = threadIdx.x;
    for (int tl = 0; tl < 8; ++tl) {
        __syncthreads();
#pragma unroll
        for (int i = 0; i < 4; ++i) {
            const int idx = t + i * 256;
            const int m = idx >> 6, rest = idx & 63;
            const int t2 = rest >> 5, k4 = rest & 31;
            float4v v = *(const float4v*)(x +
                ((size_t)(mt * 16 + m) * T_STEPS + (tb * 16 + tl * 2 + t2)) * NIN + k4 * 4);
            *(float4v*)&xs[m][t2][k4 * 4] = v;
        }
        __syncthreads();
#pragma unroll
        for (int i = 0; i < 2; ++i) {
            const int idx = t + i * 256;
            const int t2 = idx >> 8, rest = idx & 255;
            const int kt = rest >> 6, lane = rest & 63;
            half8 hv;
#pragma unroll
            for (int j = 0; j < 8; ++j)
                hv[j] = (_Float16)xs[lane & 15][t2][kt * 32 + (lane >> 4) * 8 + j];
            const int tg = tb * 16 + tl * 2 + t2;
            *(half8*)(xf + (((size_t)tg * 32 + mt) * 4 + kt) * 512 + lane * 8) = hv;
        }
    }
}

// ---------------------------------------------------------------------------
// Persistent kernel (R8 + proj issue/fin overlap + unified single-write A-buf).
// 256 WGs x 512 thr, 1 WG/CU (152 KB LDS).
// xcd = bid&7; layer = xcd>>2; s = (xcd&3)*32 + (bid>>3); u0 = s*8.
// GEMM K-loop: depth-3 counted-vmcnt inline-asm pipeline (proven).
// proj: ALL WGs, 2 mt each; its 8 xf loads issue BEFORE the gemm pipeline
// (oldest -> drained by the first vmcnt(16)); compute after WAITG(0).
// ---------------------------------------------------------------------------
__global__ __launch_bounds__(512, 2)
void persist_kernel(const float* __restrict__ k1, const float* __restrict__ b1,
                    const float* __restrict__ k2, const float* __restrict__ b2,
                    const float* __restrict__ W_h, const float* __restrict__ b_h,
                    const _Float16* __restrict__ xf,
                    uint8_t* wsb, float* __restrict__ out,
                    uint32_t* barrier_mem)
{
    extern __shared__ __align__(16) char smem[];
    const size_t MB = 1024 * 1024;
    char* AB[2] = {(char*)(wsb + 0 * MB), (char*)(wsb + 3 * MB)};

    const int tid = threadIdx.x;
    const int w = tid >> 6, lane = tid & 63;
    const int q = lane >> 4, n16 = lane & 15;
    const int bid = blockIdx.x;
    const int xcd = bid & 7;
    const int layer = xcd >> 2;              // XCDs 0-3: layer 0; 4-7: layer 1
    const int s = (xcd & 3) * 32 + (bid >> 3);   // 0..127, bijective per layer
    const int u0 = s * 8;
    const int pu0 = s * 8;                   // proj slice s (both layers, 2 mt each)

    const float* ksrc = layer ? k2 : k1;
    const float* bsrc = layer ? b2 : b1;

    // ---- init: convert weight slice f32 -> fp16 frags in LDS (proven) ----
    {
#pragma unroll 1
        for (int i = 0; i < 16; ++i) {
            const int kt = w * 8 + (i & 7);
            const int nt = i >> 3;
            const int colg = (nt * 2 + (n16 >> 3)) * 1024 + u0 + (n16 & 7);
            half8 hv;
#pragma unroll
            for (int j = 0; j < 8; ++j)
                hv[j] = (_Float16)ksrc[(size_t)(kt * 32 + q * 8 + j) * 4096 + colg];
            *(half8*)(smem + WLDS_OFF + (nt * 64 + kt) * 1024 + lane * 16) = hv;
        }
    }
    if (tid < 32)
        ((float*)(smem + BIASG_OFF))[tid] = bsrc[(tid >> 3) * 1024 + u0 + (tid & 7)];
    {   // proj weights: all WGs, slice s
        if (tid < 256) {
            const int kt = tid >> 6, ln = tid & 63;
            const int nn = ln & 15;
            half8 hv;
#pragma unroll
            for (int j = 0; j < 8; ++j) {
                float v = (nn < 8)
                    ? W_h[(size_t)(kt * 32 + (ln >> 4) * 8 + j) * NHID + pu0 + nn] : 0.f;
                hv[j] = (_Float16)v;
            }
            *(half8*)(smem + WHF_OFF + kt * 1024 + ln * 16) = hv;
        }
        if (tid < 8) ((float*)(smem + BH_OFF))[tid] = b_h[pu0 + tid];
    }
    __syncthreads();

    const float* bg = (const float*)(smem + BIASG_OFF);
    const float* bh = (const float*)(smem + BH_OFF);
    float* zw = (float*)(smem + ZS_OFF + w * ZW_BYTES);     // [16 rows][36 f32]
    _Float16* hw = (_Float16*)(smem + HS_OFF + w * 256);    // [16 rows][8 u]

    // c state: lane owns (row = n16, units q*2, q*2+1) per mt
    float cst[4][2];
#pragma unroll
    for (int mt = 0; mt < 4; ++mt) { cst[mt][0] = 0.f; cst[mt][1] = 0.f; }

    half8 Pr[8];        // proj A-frags: in flight across the gemm pipeline

    // ---- proj issue: 8 asm xf loads (oldest in the wave's VMEM queue) ----
    auto proj_issue = [&](int tstep) {
#pragma unroll
        for (int kt = 0; kt < 4; ++kt)
#pragma unroll
            for (int mi = 0; mi < 2; ++mi) {
                const char* ga = (const char*)xf +
                    (((size_t)tstep * 32 + (w * 4 + layer * 2 + mi)) * 4 + kt) * 1024
                    + lane * 16;
                asm volatile("global_load_dwordx4 %0, %1, off"
                             : "=&v"(Pr[kt * 2 + mi]) : "v"(ga));
            }
    };

    // ---- proj finish: MFMA + relu + pf frag store (Pr must be drained) ----
    auto proj_fin = [&](char* ABpo) {
        float4v pacc[2];
        pacc[0] = (float4v){0.f, 0.f, 0.f, 0.f};
        pacc[1] = (float4v){0.f, 0.f, 0.f, 0.f};
#pragma unroll
        for (int kt = 0; kt < 4; ++kt) {
            half8 Bp = *(const half8*)(smem + WHF_OFF + kt * 1024 + lane * 16);
            pacc[0] = __builtin_amdgcn_mfma_f32_16x16x32_f16(Pr[kt * 2 + 0], Bp, pacc[0], 0, 0, 0);
            pacc[1] = __builtin_amdgcn_mfma_f32_16x16x32_f16(Pr[kt * 2 + 1], Bp, pacc[1], 0, 0, 0);
        }
#pragma unroll 1
        for (int mi = 0; mi < 2; ++mi) {
            if (n16 < 8) {
#pragma unroll
                for (int r = 0; r < 4; ++r)
                    zw[(q * 4 + r) * 9 + n16] = pacc[mi][r];   // stride 9: conflict-free
            }
            if (lane < 16) {
                half8 hv;
#pragma unroll
                for (int u = 0; u < 8; ++u)
                    hv[u] = (_Float16)fmaxf(zw[lane * 9 + u] + bh[u], 0.f);
                const int mtg = w * 4 + layer * 2 + mi;
                char* dst = ABpo + (size_t)mtg * MT_STRIDE
                            + (s >> 2) * 1024 + ((s & 3) * 16 + lane) * 16;
                STORE_SC(dst, hv);
            }
        }
    };

    // ---- LSTM GEMM + fused epilogue; depth-3 counted-vmcnt asm pipeline ----
    auto gemm_step = [&](const char* Abase, char* ABpo, int hslot, float* outp) {
        float4v acc[4][2];
#pragma unroll
        for (int mt = 0; mt < 4; ++mt) {
            acc[mt][0] = (float4v){0.f, 0.f, 0.f, 0.f};
            acc[mt][1] = (float4v){0.f, 0.f, 0.f, 0.f};
        }
        const char* aw[4];
#pragma unroll
        for (int mt = 0; mt < 4; ++mt)
            aw[mt] = Abase + (size_t)(w * 4 + mt) * MT_STRIDE + lane * 16;

        half8 G0[8], G1[8], G2[8];   // 3 groups x 2 kt x 4 mt, static indexing

#define ISSUE2(buf, kb)                                                         \
        do {                                                                    \
            _Pragma("unroll")                                                   \
            for (int kk = 0; kk < 2; ++kk) {                                    \
                _Pragma("unroll")                                               \
                for (int mt = 0; mt < 4; ++mt)                                  \
                    asm volatile("global_load_dwordx4 %0, %1, off"              \
                                 : "=&v"(buf[kk * 4 + mt])                      \
                                 : "v"(aw[mt] + (size_t)((kb) + kk) * 1024));   \
            }                                                                   \
        } while (0)

#define WAITG(n, buf)                                                           \
        do {                                                                    \
            asm volatile("s_waitcnt vmcnt(" #n ")"                              \
                : "+v"(buf[0]), "+v"(buf[1]), "+v"(buf[2]), "+v"(buf[3]),       \
                  "+v"(buf[4]), "+v"(buf[5]), "+v"(buf[6]), "+v"(buf[7]));      \
            __builtin_amdgcn_sched_barrier(0);                                  \
        } while (0)

#define MFMA2(buf, kb)                                                          \
        do {                                                                    \
            _Pragma("unroll")                                                   \
            for (int kk = 0; kk < 2; ++kk) {                                    \
                half8 B0 = *(const half8*)(smem + WLDS_OFF                      \
                              + (size_t)((kb) + kk) * 1024 + lane * 16);        \
                half8 B1 = *(const half8*)(smem + WLDS_OFF + 65536              \
                              + (size_t)((kb) + kk) * 1024 + lane * 16);        \
                _Pragma("unroll")                                               \
                for (int mt = 0; mt < 4; ++mt)                                  \
                    acc[mt][0] = __builtin_amdgcn_mfma_f32_16x16x32_f16(        \
                        buf[kk * 4 + mt], B0, acc[mt][0], 0, 0, 0);             \
                _Pragma("unroll")                                               \
                for (int mt = 0; mt < 4; ++mt)                                  \
                    acc[mt][1] = __builtin_amdgcn_mfma_f32_16x16x32_f16(        \
                        buf[kk * 4 + mt], B1, acc[mt][1], 0, 0, 0);             \
            }                                                                   \
        } while (0)

        ISSUE2(G0, 0);
        ISSUE2(G1, 2);
        ISSUE2(G2, 4);      // + up to 8 proj loads issued earlier (oldest)
#pragma unroll 1
        for (int g3 = 0; g3 < 10; ++g3) {
            const int kb = g3 * 6;
            WAITG(16, G0);  MFMA2(G0, kb);      ISSUE2(G0, kb + 6);
            WAITG(16, G1);  MFMA2(G1, kb + 2);  ISSUE2(G1, kb + 8);
            WAITG(16, G2);  MFMA2(G2, kb + 4);
            if (g3 < 9) ISSUE2(G2, kb + 10);
        }
        // tail: G0 holds kt 60, G1 holds kt 62; 16 outstanding
        WAITG(8, G0);
        MFMA2(G0, 60);
        WAITG(0, G1);
        MFMA2(G1, 62);
#undef ISSUE2
#undef WAITG
#undef MFMA2

        // epilogue per mt (cols: g*8+u), zw stride 36
#pragma unroll 1
        for (int mt = 0; mt < 4; ++mt) {
#pragma unroll
            for (int nt = 0; nt < 2; ++nt)
#pragma unroll
                for (int r = 0; r < 4; ++r)
                    zw[(q * 4 + r) * 36 + nt * 16 + n16] = acc[mt][nt][r];
            const float* zr = zw + n16 * 36 + q * 2;
            float2v vi = *(const float2v*)(zr + 0);
            float2v vj = *(const float2v*)(zr + 8);
            float2v vf = *(const float2v*)(zr + 16);
            float2v vo = *(const float2v*)(zr + 24);
            float hvals[2];
#pragma unroll
            for (int uu = 0; uu < 2; ++uu) {
                const int u = q * 2 + uu;
                const float zi = vi[uu] + bg[u];
                const float zj = vj[uu] + bg[8 + u];
                const float zf = vf[uu] + bg[16 + u];
                const float zo = vo[uu] + bg[24 + u];
                float c = cst[mt][uu] * sigmoid_f(zf + 1.0f) + sigmoid_f(zi) * tanh_f(zj);
                cst[mt][uu] = c;
                hvals[uu] = tanh_f(c) * sigmoid_f(zo);
            }
            hw[n16 * 8 + q * 2 + 0] = (_Float16)hvals[0];
            hw[n16 * 8 + q * 2 + 1] = (_Float16)hvals[1];
            if (outp) {
                const int row = (w * 4 + mt) * 16 + n16;
                outp[(size_t)row * NHID + u0 + q * 2 + 0] = hvals[0];
                outp[(size_t)row * NHID + u0 + q * 2 + 1] = hvals[1];
            }
            if (lane < 16) {
                half8 hv = *(half8*)(hw + lane * 8);
                const int mtg = w * 4 + mt;
                char* d1 = ABpo + (size_t)mtg * MT_STRIDE + hslot
                           + (s >> 2) * 1024 + ((s & 3) * 16 + lane) * 16;
                STORE_SC(d1, hv);
            }
        }
    };

    // ---- pre-phase: proj(0) -> AB[0].pf ----
    proj_issue(0);
    asm volatile("s_waitcnt vmcnt(0)");
    __builtin_amdgcn_sched_barrier(0);
    proj_fin(AB[0]);
    grid_barrier(barrier_mem, 1u, xcd);

    // ---- phases ----
    for (int p = 0; p <= 256; ++p) {
        const int pi = p & 1, po = pi ^ 1;
        const bool dop = (p + 1 <= 255);
        if (dop) proj_issue(p + 1);              // rides under the gemm stream
        bool didGemm = false;
        if (layer == 0) {
            if (p <= 255) {
                gemm_step(AB[pi], AB[po], H1SLOT, nullptr);          // h1(p)
                didGemm = true;
            }
        } else {
            if (p >= 1) {
                gemm_step(AB[pi] + H1SLOT, AB[po], H2SLOT,           // h2(p-1)
                          (p == 256) ? out : nullptr);
                didGemm = true;
            }
        }
        if (dop) {
            if (!didGemm) {
                asm volatile("s_waitcnt vmcnt(0)");
                __builtin_amdgcn_sched_barrier(0);
            }
            proj_fin(AB[po]);                    // pf(p+1)
        }
        grid_barrier(barrier_mem, (uint32_t)(p + 2), xcd);
    }
}

// ---------------------------------------------------------------------------
extern "C" void kernel_launch(void* const* d_in, const int* in_sizes, int n_in,
                              void* d_out, int out_size, void* d_ws, size_t ws_size,
                              hipStream_t stream)
{
    const float* x   = (const float*)d_in[0];
    const float* W_h = (const float*)d_in[1];
    const float* b_h = (const float*)d_in[2];
    const float* k1  = (const float*)d_in[3];
    const float* b1  = (const float*)d_in[4];
    const float* k2  = (const float*)d_in[5];
    const float* b2  = (const float*)d_in[6];
    float* out = (float*)d_out;

    const size_t MB = 1024 * 1024;
    uint8_t* wsb = (uint8_t*)d_ws;
    // AB[0] 0-3 MB, AB[1] 3-6 MB (unified [pf|h1|h2] stripes, zeroed)
    // xf 8-40 MB ; barrier @ 40 MB
    _Float16* xf = (_Float16*)(wsb + 8 * MB);
    uint32_t* barrier_mem = (uint32_t*)(wsb + 40 * MB);

    hipFuncSetAttribute((const void*)persist_kernel,
                        hipFuncAttributeMaxDynamicSharedMemorySize, SMEM_BYTES);

    hipMemsetAsync(wsb, 0, 6 * MB, stream);          // zero A-buffers
    hipMemsetAsync(barrier_mem, 0, 4096, stream);
    xconv_kernel<<<dim3(32, 16), 256, 0, stream>>>(x, xf);
    persist_kernel<<<NWGS, 512, SMEM_BYTES, stream>>>(
        k1, b1, k2, b2, W_h, b_h, xf, wsb, out, barrier_mem);
}